// Round 1
// baseline (546.640 us; speedup 1.0000x reference)
//
#include <hip/hip_runtime.h>
#include <stdint.h>

#define T_TOK 4096
#define DIN   2048
#define DQ    2048
#define DKV   2048
#define NOUT  (DQ + 2*DKV)         /* 6144 */
#define NA    4
#define RLORA 16
#define BM    128
#define BN    128
#define MPAD  (T_TOK + NA*BM)      /* 4608 */
#define MTILES (MPAD/BM)           /* 36 */

typedef unsigned short u16;
typedef __attribute__((ext_vector_type(8))) short short8;
typedef __attribute__((ext_vector_type(8))) u16 u16x8;
typedef __attribute__((ext_vector_type(4))) float f32x4;

__device__ __forceinline__ u16 f2bf(float f) {
  uint32_t u = __float_as_uint(f);
  u = (u + 0x7FFFu + ((u >> 16) & 1u)) >> 16;
  return (u16)u;
}

typedef __attribute__((address_space(3))) void lds_void;
typedef __attribute__((address_space(1))) void glb_void;

__device__ __forceinline__ void gl_lds16(const void* g, void* l) {
  __builtin_amdgcn_global_load_lds((const glb_void*)(uintptr_t)g,
                                   (lds_void*)(uint32_t)(uintptr_t)l, 16, 0, 0);
}

// ---------------------------------------------------------------------------
// Kernel 1: stable counting sort of tokens by adapter, padded to BM multiples.
// tok[row] = original token index (or -1 for padding), tileAdapter[tile] = a.
// ---------------------------------------------------------------------------
__global__ void prep_kernel(const int* __restrict__ widx,
                            int* __restrict__ tok,
                            int* __restrict__ tileAdapter) {
  __shared__ int cnt[256][NA];
  __shared__ int total[NA];
  __shared__ int pad_off[NA];
  const int tid = threadIdx.x;
  const int CH = T_TOK / 256;  // 16
  const int base = tid * CH;
  int c[NA] = {0, 0, 0, 0};
  for (int i = 0; i < CH; i++) c[widx[base + i]]++;
  for (int a = 0; a < NA; a++) cnt[tid][a] = c[a];
  __syncthreads();
  if (tid < NA) {
    int s = 0;
    for (int i = 0; i < 256; i++) { int v = cnt[i][tid]; cnt[i][tid] = s; s += v; }
    total[tid] = s;
  }
  __syncthreads();
  if (tid == 0) {
    int off = 0;
    for (int a = 0; a < NA; a++) {
      pad_off[a] = off;
      int ntile = (total[a] + BM - 1) / BM;
      for (int tl = 0; tl < ntile; tl++) tileAdapter[off / BM + tl] = a;
      off += ntile * BM;
    }
    for (int tl = off / BM; tl < MTILES; tl++) tileAdapter[tl] = 0;
  }
  __syncthreads();
  for (int i = tid; i < MPAD; i += 256) tok[i] = -1;
  __syncthreads();
  int myoff[NA];
  for (int a = 0; a < NA; a++) myoff[a] = pad_off[a] + cnt[tid][a];
  for (int i = 0; i < CH; i++) {
    int a = widx[base + i];
    tok[myoff[a]++] = base + i;
  }
}

// ---------------------------------------------------------------------------
// Kernel 2: build Weff[a][n][k] = W_base[n][k] + Delta[a][k][n] + sum_r A*B,
// converted to bf16.  64x64 (n x k) tile per block, one adapter per z.
// ---------------------------------------------------------------------------
__global__ void weff_kernel(const float* __restrict__ W_base,
                            const float* __restrict__ A_qkv,
                            const float* __restrict__ B_q,
                            const float* __restrict__ B_kv,
                            const float* __restrict__ DW_q,
                            const float* __restrict__ DW_kv,
                            u16* __restrict__ Weff) {
  const int k0 = blockIdx.x * 64;
  const int n0 = blockIdx.y * 64;
  const int a  = blockIdx.z;
  __shared__ float ldsD[64][65];
  __shared__ float ldsB[16][65];
  __shared__ float ldsA[64][17];

  const float* Dptr; int ldD, ncol, roff;
  const float* Bptr; int ldB;
  if (n0 < DQ) {
    Dptr = DW_q + (size_t)a * DIN * DQ;  ldD = DQ;  ncol = n0;
    Bptr = B_q  + (size_t)a * RLORA * DQ; ldB = DQ;  roff = 0;
  } else {
    Dptr = DW_kv + (size_t)a * DIN * (2 * DKV); ldD = 2 * DKV; ncol = n0 - DQ;
    Bptr = B_kv  + (size_t)a * RLORA * (2 * DKV); ldB = 2 * DKV;
    roff = (n0 < 2 * DQ) ? RLORA : 2 * RLORA;
  }
  const int tid = threadIdx.x;
  for (int i = tid; i < 64 * 64; i += 256) {
    int kk = i >> 6, nn = i & 63;
    ldsD[kk][nn] = Dptr[(size_t)(k0 + kk) * ldD + ncol + nn];
  }
  for (int i = tid; i < RLORA * 64; i += 256) {
    int r = i >> 6, nn = i & 63;
    ldsB[r][nn] = Bptr[(size_t)r * ldB + ncol + nn];
  }
  for (int i = tid; i < 64 * RLORA; i += 256) {
    int kk = i >> 4, r = i & 15;
    ldsA[kk][r] = A_qkv[((size_t)a * DIN + k0 + kk) * (3 * RLORA) + roff + r];
  }
  __syncthreads();

  #pragma unroll
  for (int it = 0; it < 2; it++) {
    int wi = it * 256 + tid;        // 0..511
    int nn = wi >> 3;               // 0..63
    int k8 = (wi & 7) * 8;          // 0..56
    const float* wb = W_base + (size_t)(n0 + nn) * DIN + k0 + k8;
    f32x4 w0 = *(const f32x4*)(wb);
    f32x4 w1 = *(const f32x4*)(wb + 4);
    u16x8 o;
    #pragma unroll
    for (int j = 0; j < 8; j++) {
      float val = (j < 4 ? w0[j & 3] : w1[j & 3]) + ldsD[k8 + j][nn];
      #pragma unroll
      for (int r = 0; r < RLORA; r++) val += ldsA[k8 + j][r] * ldsB[r][nn];
      o[j] = f2bf(val);
    }
    *(u16x8*)(Weff + ((size_t)a * NOUT + n0 + nn) * DIN + k0 + k8) = o;
  }
}

// ---------------------------------------------------------------------------
// Kernel 3: gather x rows into sorted order, convert to bf16 (zeros for pad).
// ---------------------------------------------------------------------------
__global__ void gather_kernel(const float* __restrict__ x,
                              const int* __restrict__ tok,
                              u16* __restrict__ Xg) {
  const int row = blockIdx.x;
  const int t = tok[row];
  const int tid = threadIdx.x;
  u16x8* dst = (u16x8*)(Xg + (size_t)row * DIN);
  if (t < 0) {
    u16x8 z = {0, 0, 0, 0, 0, 0, 0, 0};
    dst[tid] = z;
    return;
  }
  const f32x4* src = (const f32x4*)(x + (size_t)t * DIN);
  f32x4 v0 = src[tid * 2];
  f32x4 v1 = src[tid * 2 + 1];
  u16x8 o;
  o[0] = f2bf(v0[0]); o[1] = f2bf(v0[1]); o[2] = f2bf(v0[2]); o[3] = f2bf(v0[3]);
  o[4] = f2bf(v1[0]); o[5] = f2bf(v1[1]); o[6] = f2bf(v1[2]); o[7] = f2bf(v1[3]);
  dst[tid] = o;
}

// ---------------------------------------------------------------------------
// Kernel 4: grouped GEMM  out[tok[m]] = Xg[m] @ Weff[a]^T   (bf16 MFMA)
// 128x128 tile, BK=32, 4 waves each computing 64x64 (4x4 fragments 16x16x32).
// global_load_lds width-16 staging into linear LDS (m97 structure).
// ---------------------------------------------------------------------------
__global__ __launch_bounds__(256) void gemm_kernel(
    const u16* __restrict__ Xg, const u16* __restrict__ Weff,
    const int* __restrict__ tok, const int* __restrict__ tileAdapter,
    float* __restrict__ out) {
  __shared__ __align__(16) u16 As[BM * 32];
  __shared__ __align__(16) u16 Bs[BN * 32];
  const int mt = blockIdx.x, nt = blockIdx.y;
  const int m0 = mt * BM, n0 = nt * BN;
  const int a = tileAdapter[mt];
  const u16* Wp = Weff + (size_t)a * NOUT * DIN;
  const int tid = threadIdx.x;
  const int w = tid >> 6, l = tid & 63;
  const int rowq = (w << 4) + (l >> 2);   // 0..63 (q adds 64)
  const int kseg = (l & 3) << 3;          // 0,8,16,24
  const int wrow = (w >> 1) << 6, wcol = (w & 1) << 6;

  f32x4 acc[4][4];
  #pragma unroll
  for (int mi = 0; mi < 4; mi++)
    #pragma unroll
    for (int ni = 0; ni < 4; ni++) acc[mi][ni] = (f32x4){0.f, 0.f, 0.f, 0.f};

  const u16* gA = Xg + (size_t)(m0 + rowq) * DIN + kseg;
  const u16* gB = Wp + (size_t)(n0 + rowq) * DIN + kseg;
  u16* lA = As + ((w << 6) + l) * 8;
  u16* lB = Bs + ((w << 6) + l) * 8;
  const int lrow = l & 15, lk = (l >> 4) << 3;

  for (int kt = 0; kt < DIN; kt += 32) {
    gl_lds16(gA + kt, lA);
    gl_lds16(gA + kt + (size_t)64 * DIN, lA + 2048);
    gl_lds16(gB + kt, lB);
    gl_lds16(gB + kt + (size_t)64 * DIN, lB + 2048);
    __syncthreads();
    short8 af[4], bf[4];
    #pragma unroll
    for (int mi = 0; mi < 4; mi++)
      af[mi] = *(const short8*)(As + (wrow + mi * 16 + lrow) * 32 + lk);
    #pragma unroll
    for (int ni = 0; ni < 4; ni++)
      bf[ni] = *(const short8*)(Bs + (wcol + ni * 16 + lrow) * 32 + lk);
    #pragma unroll
    for (int mi = 0; mi < 4; mi++)
      #pragma unroll
      for (int ni = 0; ni < 4; ni++)
        acc[mi][ni] = __builtin_amdgcn_mfma_f32_16x16x32_bf16(af[mi], bf[ni],
                                                              acc[mi][ni], 0, 0, 0);
    __syncthreads();
  }

  #pragma unroll
  for (int mi = 0; mi < 4; mi++) {
    const int rbase = m0 + wrow + mi * 16 + ((l >> 4) << 2);
    #pragma unroll
    for (int reg = 0; reg < 4; reg++) {
      const int t = tok[rbase + reg];
      if (t < 0) continue;
      float* orow = out + (size_t)t * NOUT + n0 + wcol + (l & 15);
      #pragma unroll
      for (int ni = 0; ni < 4; ni++) orow[ni * 16] = acc[mi][ni][reg];
    }
  }
}

// ---------------------------------------------------------------------------
// Fallback (ws too small): correct fp32 path, LDS-staged x row per block.
// ---------------------------------------------------------------------------
__global__ void fallback_kernel(const float* __restrict__ x,
                                const float* __restrict__ W_base,
                                const float* __restrict__ A_qkv,
                                const float* __restrict__ B_q,
                                const float* __restrict__ B_kv,
                                const float* __restrict__ DW_q,
                                const float* __restrict__ DW_kv,
                                const int* __restrict__ widx,
                                float* __restrict__ out) {
  const int t = blockIdx.x;
  const int n = blockIdx.y * 256 + threadIdx.x;
  const int a = widx[t];
  __shared__ float xs[DIN];
  __shared__ float ys[3 * RLORA];
  for (int k = threadIdx.x; k < DIN; k += 256) xs[k] = x[(size_t)t * DIN + k];
  __syncthreads();
  if (threadIdx.x < 3 * RLORA) {
    float s = 0.f;
    const float* Ap = A_qkv + (size_t)a * DIN * (3 * RLORA) + threadIdx.x;
    for (int k = 0; k < DIN; k++) s += xs[k] * Ap[(size_t)k * (3 * RLORA)];
    ys[threadIdx.x] = s;
  }
  __syncthreads();
  const float* dcol; int ldD, roff; const float* bcol; int ldB;
  if (n < DQ) {
    dcol = DW_q + (size_t)a * DIN * DQ + n; ldD = DQ; roff = 0;
    bcol = B_q + (size_t)a * RLORA * DQ + n; ldB = DQ;
  } else {
    dcol = DW_kv + (size_t)a * DIN * (2 * DKV) + (n - DQ); ldD = 2 * DKV;
    roff = (n < 2 * DQ) ? RLORA : 2 * RLORA;
    bcol = B_kv + (size_t)a * RLORA * (2 * DKV) + (n - DQ); ldB = 2 * DKV;
  }
  const float* wrow = W_base + (size_t)n * DIN;
  float acc = 0.f;
  for (int k = 0; k < DIN; k++) acc += xs[k] * (wrow[k] + dcol[(size_t)k * ldD]);
  for (int r = 0; r < RLORA; r++) acc += ys[roff + r] * bcol[(size_t)r * ldB];
  out[(size_t)t * NOUT + n] = acc;
}

// ---------------------------------------------------------------------------
extern "C" void kernel_launch(void* const* d_in, const int* in_sizes, int n_in,
                              void* d_out, int out_size, void* d_ws, size_t ws_size,
                              hipStream_t stream) {
  const float* x      = (const float*)d_in[0];
  const float* W_base = (const float*)d_in[1];
  const float* A_qkv  = (const float*)d_in[2];
  const float* B_q    = (const float*)d_in[3];
  const float* B_kv   = (const float*)d_in[4];
  const float* DW_q   = (const float*)d_in[5];
  const float* DW_kv  = (const float*)d_in[6];
  const int*   widx   = (const int*)d_in[7];
  float* out = (float*)d_out;

  const size_t WEFF_BYTES = (size_t)NA * NOUT * DIN * sizeof(u16);   // 100.7 MB
  const size_t XG_BYTES   = (size_t)MPAD * DIN * sizeof(u16);        // 18.9 MB
  const size_t TOK_BYTES  = (size_t)MPAD * sizeof(int);
  const size_t TILE_BYTES = (size_t)MTILES * sizeof(int);
  const size_t need = WEFF_BYTES + XG_BYTES + TOK_BYTES + TILE_BYTES;

  if (ws_size < need) {
    fallback_kernel<<<dim3(T_TOK, NOUT / 256), 256, 0, stream>>>(
        x, W_base, A_qkv, B_q, B_kv, DW_q, DW_kv, widx, out);
    return;
  }

  char* ws = (char*)d_ws;
  u16* Weff = (u16*)ws;
  u16* Xg   = (u16*)(ws + WEFF_BYTES);
  int* tok  = (int*)(ws + WEFF_BYTES + XG_BYTES);
  int* tileAdapter = tok + MPAD;

  prep_kernel<<<1, 256, 0, stream>>>(widx, tok, tileAdapter);
  weff_kernel<<<dim3(DIN / 64, NOUT / 64, NA), 256, 0, stream>>>(
      W_base, A_qkv, B_q, B_kv, DW_q, DW_kv, Weff);
  gather_kernel<<<MPAD, 256, 0, stream>>>(x, tok, Xg);
  gemm_kernel<<<dim3(MTILES, NOUT / BN), 256, 0, stream>>>(
      Xg, Weff, tok, tileAdapter, out);
}

// Round 2
// 349.710 us; speedup vs baseline: 1.5631x; 1.5631x over previous
//
#include <hip/hip_runtime.h>
#include <stdint.h>

#define T_TOK 4096
#define DIN   2048
#define DQ    2048
#define DKV   2048
#define NOUT  (DQ + 2*DKV)         /* 6144 */
#define NA    4
#define RLORA 16
#define BM    128
#define BN    128
#define MPAD  (T_TOK + NA*BM)      /* 4608 */
#define MTILES (MPAD/BM)           /* 36 */
#define KX    (DIN + 64)           /* 2112: extended K with LoRA slots */
#define KSPLIT 16

typedef unsigned short u16;
typedef __attribute__((ext_vector_type(8))) short short8;
typedef __attribute__((ext_vector_type(8))) u16 u16x8;
typedef __attribute__((ext_vector_type(4))) float f32x4;

__device__ __forceinline__ u16 f2bf(float f) {
  uint32_t u = __float_as_uint(f);
  u = (u + 0x7FFFu + ((u >> 16) & 1u)) >> 16;
  return (u16)u;
}
__device__ __forceinline__ float bf2f(u16 u) {
  return __uint_as_float(((uint32_t)u) << 16);
}

typedef __attribute__((address_space(3))) void lds_void;
typedef __attribute__((address_space(1))) void glb_void;

__device__ __forceinline__ void gl_lds16(const void* g, void* l) {
  __builtin_amdgcn_global_load_lds((const glb_void*)(uintptr_t)g,
                                   (lds_void*)(uint32_t)(uintptr_t)l, 16, 0, 0);
}

// ---------------------------------------------------------------------------
// Kernel 1: stable counting sort of tokens by adapter, padded to BM multiples.
// ---------------------------------------------------------------------------
__global__ void prep_kernel(const int* __restrict__ widx,
                            int* __restrict__ tok,
                            int* __restrict__ tileAdapter) {
  __shared__ int cnt[256][NA];
  __shared__ int total[NA];
  __shared__ int pad_off[NA];
  const int tid = threadIdx.x;
  const int CH = T_TOK / 256;  // 16
  const int base = tid * CH;
  int c[NA] = {0, 0, 0, 0};
  for (int i = 0; i < CH; i++) c[widx[base + i]]++;
  for (int a = 0; a < NA; a++) cnt[tid][a] = c[a];
  __syncthreads();
  if (tid < NA) {
    int s = 0;
    for (int i = 0; i < 256; i++) { int v = cnt[i][tid]; cnt[i][tid] = s; s += v; }
    total[tid] = s;
  }
  __syncthreads();
  if (tid == 0) {
    int off = 0;
    for (int a = 0; a < NA; a++) {
      pad_off[a] = off;
      int ntile = (total[a] + BM - 1) / BM;
      for (int tl = 0; tl < ntile; tl++) tileAdapter[off / BM + tl] = a;
      off += ntile * BM;
    }
    for (int tl = off / BM; tl < MTILES; tl++) tileAdapter[tl] = 0;
  }
  __syncthreads();
  for (int i = tid; i < MPAD; i += 256) tok[i] = -1;
  __syncthreads();
  int myoff[NA];
  for (int a = 0; a < NA; a++) myoff[a] = pad_off[a] + cnt[tid][a];
  for (int i = 0; i < CH; i++) {
    int a = widx[base + i];
    tok[myoff[a]++] = base + i;
  }
}

// ---------------------------------------------------------------------------
// Kernel 2: gather x rows into sorted order -> bf16 (cols 0..2047 of Xg).
// ---------------------------------------------------------------------------
__global__ void gather_kernel(const float* __restrict__ x,
                              const int* __restrict__ tok,
                              u16* __restrict__ Xg) {
  const int row = blockIdx.x;
  const int t = tok[row];
  const int tid = threadIdx.x;
  u16x8* dst = (u16x8*)(Xg + (size_t)row * KX);
  if (t < 0) {
    u16x8 z = {0, 0, 0, 0, 0, 0, 0, 0};
    dst[tid] = z;
    return;
  }
  const f32x4* src = (const f32x4*)(x + (size_t)t * DIN);
  f32x4 v0 = src[tid * 2];
  f32x4 v1 = src[tid * 2 + 1];
  u16x8 o;
  o[0] = f2bf(v0[0]); o[1] = f2bf(v0[1]); o[2] = f2bf(v0[2]); o[3] = f2bf(v0[3]);
  o[4] = f2bf(v1[0]); o[5] = f2bf(v1[1]); o[6] = f2bf(v1[2]); o[7] = f2bf(v1[3]);
  dst[tid] = o;
}

// ---------------------------------------------------------------------------
// Kernel 3: Xa partials.  Xa = Xg[:, :2048] @ A_qkv[a]  ([M x 48]).
// Grid (MTILES, KSPLIT); thread owns 2 rows x 12 cols; A chunk staged in LDS
// read as broadcast f32x4.  Partials to Ppart[ks][row][48] (aliases Weff).
// ---------------------------------------------------------------------------
__global__ __launch_bounds__(256) void xa_partial_kernel(
    const u16* __restrict__ Xg, const float* __restrict__ A_qkv,
    const int* __restrict__ tileAdapter, float* __restrict__ Ppart) {
  const int mt = blockIdx.x, ks = blockIdx.y;
  const int a = tileAdapter[mt];
  const int m0 = mt * BM;
  const int kb = ks * (DIN / KSPLIT);   // 128-wide K slice
  const int tid = threadIdx.x;
  const int rg = tid >> 2;              // 0..63
  const int jg = tid & 3;               // 0..3
  const int r0 = m0 + rg * 2;
  const int j0 = jg * 12;
  __shared__ float ldsA[64][56];        // row 224B (16-mult), 48 used
  float acc[2][12];
  #pragma unroll
  for (int r = 0; r < 2; r++)
    #pragma unroll
    for (int j = 0; j < 12; j++) acc[r][j] = 0.f;

  for (int kc = 0; kc < 2; kc++) {
    const int kbase = kb + kc * 64;
    for (int i = tid; i < 64 * 48; i += 256) {
      int kk = i / 48, j = i - kk * 48;
      ldsA[kk][j] = A_qkv[((size_t)a * DIN + kbase + kk) * (3 * RLORA) + j];
    }
    __syncthreads();
    u16x8 xr[2][8];
    #pragma unroll
    for (int r = 0; r < 2; r++)
      #pragma unroll
      for (int q = 0; q < 8; q++)
        xr[r][q] = *(const u16x8*)(Xg + (size_t)(r0 + r) * KX + kbase + q * 8);
    #pragma unroll
    for (int q = 0; q < 8; q++) {
      #pragma unroll
      for (int e = 0; e < 8; e++) {
        const int kk = q * 8 + e;
        f32x4 a0 = *(const f32x4*)&ldsA[kk][j0];
        f32x4 a1 = *(const f32x4*)&ldsA[kk][j0 + 4];
        f32x4 a2 = *(const f32x4*)&ldsA[kk][j0 + 8];
        float x0 = bf2f(xr[0][q][e]);
        float x1 = bf2f(xr[1][q][e]);
        #pragma unroll
        for (int c = 0; c < 4; c++) {
          acc[0][c]     += x0 * a0[c];  acc[1][c]     += x1 * a0[c];
          acc[0][4 + c] += x0 * a1[c];  acc[1][4 + c] += x1 * a1[c];
          acc[0][8 + c] += x0 * a2[c];  acc[1][8 + c] += x1 * a2[c];
        }
      }
    }
    __syncthreads();
  }
  #pragma unroll
  for (int r = 0; r < 2; r++)
    #pragma unroll
    for (int j = 0; j < 12; j++)
      Ppart[((size_t)ks * MPAD + r0 + r) * 48 + j0 + j] = acc[r][j];
}

// ---------------------------------------------------------------------------
// Kernel 4: reduce partials -> bf16 into Xg cols 2048..2111 (j>=48 zero).
// ---------------------------------------------------------------------------
__global__ void xa_reduce_kernel(const float* __restrict__ Ppart,
                                 u16* __restrict__ Xg) {
  const int gid = blockIdx.x * 256 + threadIdx.x;
  const int row = gid >> 6, j = gid & 63;
  float s = 0.f;
  if (j < 48) {
    #pragma unroll
    for (int sp = 0; sp < KSPLIT; sp++)
      s += Ppart[((size_t)sp * MPAD + row) * 48 + j];
  }
  Xg[(size_t)row * KX + DIN + j] = f2bf(s);
}

// ---------------------------------------------------------------------------
// Kernel 5: Weff[a][n][k] = W_base[n][k] + Delta[a][k][n], bf16, k<2048.
// One block per (k0,n0) handles ALL adapters -> W_base fetched exactly once.
// ---------------------------------------------------------------------------
__global__ __launch_bounds__(256) void weff2_kernel(
    const float* __restrict__ W_base,
    const float* __restrict__ DW_q, const float* __restrict__ DW_kv,
    u16* __restrict__ Weff) {
  const int k0 = blockIdx.x * 64;
  const int n0 = blockIdx.y * 64;
  const int tid = threadIdx.x;
  const int k8 = (tid & 7) * 8;
  __shared__ float ldsD[64][65];

  f32x4 wb[2][2];
  #pragma unroll
  for (int h = 0; h < 2; h++) {
    const int nn = h * 32 + (tid >> 3);
    const float* p = W_base + (size_t)(n0 + nn) * DIN + k0 + k8;
    wb[h][0] = *(const f32x4*)p;
    wb[h][1] = *(const f32x4*)(p + 4);
  }

  const int ldD  = (n0 < DQ) ? DQ : 2 * DKV;
  const int ncol = (n0 < DQ) ? n0 : n0 - DQ;

  for (int a = 0; a < NA; a++) {
    const float* Dp = (n0 < DQ)
        ? DW_q  + (size_t)a * DIN * DQ + ncol
        : DW_kv + (size_t)a * DIN * (2 * DKV) + ncol;
    for (int i = tid; i < 64 * 64; i += 256) {
      int kk = i >> 6, nn2 = i & 63;
      ldsD[kk][nn2] = Dp[(size_t)(k0 + kk) * ldD + nn2];
    }
    __syncthreads();
    #pragma unroll
    for (int h = 0; h < 2; h++) {
      const int nn = h * 32 + (tid >> 3);
      u16x8 o;
      #pragma unroll
      for (int j = 0; j < 8; j++)
        o[j] = f2bf(wb[h][j >> 2][j & 3] + ldsD[k8 + j][nn]);
      *(u16x8*)(Weff + ((size_t)a * NOUT + n0 + nn) * KX + k0 + k8) = o;
    }
    __syncthreads();
  }
}

// ---------------------------------------------------------------------------
// Kernel 6: fill Weff[a][n][2048..2111] with scattered B (LoRA slots).
// ---------------------------------------------------------------------------
__global__ void wslots_kernel(const float* __restrict__ B_q,
                              const float* __restrict__ B_kv,
                              u16* __restrict__ Weff) {
  const int a = blockIdx.y;
  const int n = blockIdx.x * 256 + threadIdx.x;
  const int seg = n >> 11;   // 0=q, 1=k, 2=v
  u16 vals[64];
  #pragma unroll
  for (int j = 0; j < 64; j++) vals[j] = 0;
  if (seg == 0) {
    const float* Bp = B_q + ((size_t)a * RLORA) * DQ + n;
    for (int r = 0; r < RLORA; r++) vals[r] = f2bf(Bp[(size_t)r * DQ]);
  } else {
    const float* Bp = B_kv + ((size_t)a * RLORA) * (2 * DKV) + (n - DQ);
    for (int r = 0; r < RLORA; r++)
      vals[seg * RLORA + r] = f2bf(Bp[(size_t)r * (2 * DKV)]);
  }
  u16* dst = Weff + ((size_t)a * NOUT + n) * KX + DIN;
  #pragma unroll
  for (int v = 0; v < 8; v++) *(u16x8*)(dst + v * 8) = *(u16x8*)(vals + v * 8);
}

// ---------------------------------------------------------------------------
// Kernel 7: grouped GEMM  out[tok[m]] = Xg[m] @ Weff[a]^T   (bf16 MFMA)
// 128x128 tile, BK=32, K = 2112 (base+delta+LoRA in one pass).
// ---------------------------------------------------------------------------
__global__ __launch_bounds__(256) void gemm_kernel(
    const u16* __restrict__ Xg, const u16* __restrict__ Weff,
    const int* __restrict__ tok, const int* __restrict__ tileAdapter,
    float* __restrict__ out) {
  __shared__ __align__(16) u16 As[BM * 32];
  __shared__ __align__(16) u16 Bs[BN * 32];
  const int mt = blockIdx.x, nt = blockIdx.y;
  const int m0 = mt * BM, n0 = nt * BN;
  const int a = tileAdapter[mt];
  const u16* Wp = Weff + (size_t)a * NOUT * KX;
  const int tid = threadIdx.x;
  const int w = tid >> 6, l = tid & 63;
  const int rowq = (w << 4) + (l >> 2);   // 0..63
  const int kseg = (l & 3) << 3;          // 0,8,16,24
  const int wrow = (w >> 1) << 6, wcol = (w & 1) << 6;

  f32x4 acc[4][4];
  #pragma unroll
  for (int mi = 0; mi < 4; mi++)
    #pragma unroll
    for (int ni = 0; ni < 4; ni++) acc[mi][ni] = (f32x4){0.f, 0.f, 0.f, 0.f};

  const u16* gA = Xg + (size_t)(m0 + rowq) * KX + kseg;
  const u16* gB = Wp + (size_t)(n0 + rowq) * KX + kseg;
  u16* lA = As + ((w << 6) + l) * 8;
  u16* lB = Bs + ((w << 6) + l) * 8;
  const int lrow = l & 15, lk = (l >> 4) << 3;

  for (int kt = 0; kt < KX; kt += 32) {
    gl_lds16(gA + kt, lA);
    gl_lds16(gA + kt + (size_t)64 * KX, lA + 2048);
    gl_lds16(gB + kt, lB);
    gl_lds16(gB + kt + (size_t)64 * KX, lB + 2048);
    __syncthreads();
    short8 af[4], bf[4];
    #pragma unroll
    for (int mi = 0; mi < 4; mi++)
      af[mi] = *(const short8*)(As + (wrow + mi * 16 + lrow) * 32 + lk);
    #pragma unroll
    for (int ni = 0; ni < 4; ni++)
      bf[ni] = *(const short8*)(Bs + (wcol + ni * 16 + lrow) * 32 + lk);
    #pragma unroll
    for (int mi = 0; mi < 4; mi++)
      #pragma unroll
      for (int ni = 0; ni < 4; ni++)
        acc[mi][ni] = __builtin_amdgcn_mfma_f32_16x16x32_bf16(af[mi], bf[ni],
                                                              acc[mi][ni], 0, 0, 0);
    __syncthreads();
  }

  #pragma unroll
  for (int mi = 0; mi < 4; mi++) {
    const int rbase = m0 + wrow + mi * 16 + ((l >> 4) << 2);
    #pragma unroll
    for (int reg = 0; reg < 4; reg++) {
      const int t = tok[rbase + reg];
      if (t < 0) continue;
      float* orow = out + (size_t)t * NOUT + n0 + wcol + (l & 15);
      #pragma unroll
      for (int ni = 0; ni < 4; ni++) orow[ni * 16] = acc[mi][ni][reg];
    }
  }
}

// ---------------------------------------------------------------------------
// Fallback (ws too small): correct fp32 path.
// ---------------------------------------------------------------------------
__global__ void fallback_kernel(const float* __restrict__ x,
                                const float* __restrict__ W_base,
                                const float* __restrict__ A_qkv,
                                const float* __restrict__ B_q,
                                const float* __restrict__ B_kv,
                                const float* __restrict__ DW_q,
                                const float* __restrict__ DW_kv,
                                const int* __restrict__ widx,
                                float* __restrict__ out) {
  const int t = blockIdx.x;
  const int n = blockIdx.y * 256 + threadIdx.x;
  const int a = widx[t];
  __shared__ float xs[DIN];
  __shared__ float ys[3 * RLORA];
  for (int k = threadIdx.x; k < DIN; k += 256) xs[k] = x[(size_t)t * DIN + k];
  __syncthreads();
  if (threadIdx.x < 3 * RLORA) {
    float s = 0.f;
    const float* Ap = A_qkv + (size_t)a * DIN * (3 * RLORA) + threadIdx.x;
    for (int k = 0; k < DIN; k++) s += xs[k] * Ap[(size_t)k * (3 * RLORA)];
    ys[threadIdx.x] = s;
  }
  __syncthreads();
  const float* dcol; int ldD, roff; const float* bcol; int ldB;
  if (n < DQ) {
    dcol = DW_q + (size_t)a * DIN * DQ + n; ldD = DQ; roff = 0;
    bcol = B_q + (size_t)a * RLORA * DQ + n; ldB = DQ;
  } else {
    dcol = DW_kv + (size_t)a * DIN * (2 * DKV) + (n - DQ); ldD = 2 * DKV;
    roff = (n < 2 * DQ) ? RLORA : 2 * RLORA;
    bcol = B_kv + (size_t)a * RLORA * (2 * DKV) + (n - DQ); ldB = 2 * DKV;
  }
  const float* wrow = W_base + (size_t)n * DIN;
  float acc = 0.f;
  for (int k = 0; k < DIN; k++) acc += xs[k] * (wrow[k] + dcol[(size_t)k * ldD]);
  for (int r = 0; r < RLORA; r++) acc += ys[roff + r] * bcol[(size_t)r * ldB];
  out[(size_t)t * NOUT + n] = acc;
}

// ---------------------------------------------------------------------------
extern "C" void kernel_launch(void* const* d_in, const int* in_sizes, int n_in,
                              void* d_out, int out_size, void* d_ws, size_t ws_size,
                              hipStream_t stream) {
  const float* x      = (const float*)d_in[0];
  const float* W_base = (const float*)d_in[1];
  const float* A_qkv  = (const float*)d_in[2];
  const float* B_q    = (const float*)d_in[3];
  const float* B_kv   = (const float*)d_in[4];
  const float* DW_q   = (const float*)d_in[5];
  const float* DW_kv  = (const float*)d_in[6];
  const int*   widx   = (const int*)d_in[7];
  float* out = (float*)d_out;

  const size_t WEFF_BYTES = (size_t)NA * NOUT * KX * sizeof(u16);   // 103.8 MB
  const size_t XG_BYTES   = (size_t)MPAD * KX * sizeof(u16);        // 19.5 MB
  const size_t TOK_BYTES  = (size_t)MPAD * sizeof(int);
  const size_t TILE_BYTES = (size_t)MTILES * sizeof(int);
  const size_t need = WEFF_BYTES + XG_BYTES + TOK_BYTES + TILE_BYTES;

  if (ws_size < need) {
    fallback_kernel<<<dim3(T_TOK, NOUT / 256), 256, 0, stream>>>(
        x, W_base, A_qkv, B_q, B_kv, DW_q, DW_kv, widx, out);
    return;
  }

  char* ws = (char*)d_ws;
  u16* Weff = (u16*)ws;
  u16* Xg   = (u16*)(ws + WEFF_BYTES);
  int* tok  = (int*)(ws + WEFF_BYTES + XG_BYTES);
  int* tileAdapter = tok + MPAD;
  // Xa partial buffer aliases the Weff region (consumed by xa_reduce BEFORE
  // weff2 writes Weff; stream-serialized). 16*4608*48*4 = 14.2 MB < 103.8 MB.
  float* Ppart = (float*)ws;

  prep_kernel<<<1, 256, 0, stream>>>(widx, tok, tileAdapter);
  gather_kernel<<<MPAD, 256, 0, stream>>>(x, tok, Xg);
  xa_partial_kernel<<<dim3(MTILES, KSPLIT), 256, 0, stream>>>(
      Xg, A_qkv, tileAdapter, Ppart);
  xa_reduce_kernel<<<MPAD * 64 / 256, 256, 0, stream>>>(Ppart, Xg);
  weff2_kernel<<<dim3(DIN / 64, NOUT / 64), 256, 0, stream>>>(
      W_base, DW_q, DW_kv, Weff);
  wslots_kernel<<<dim3(NOUT / 256, NA), 256, 0, stream>>>(B_q, B_kv, Weff);
  gemm_kernel<<<dim3(MTILES, NOUT / BN), 256, 0, stream>>>(
      Xg, Weff, tok, tileAdapter, out);
}

// Round 3
// 266.599 us; speedup vs baseline: 2.0504x; 1.3117x over previous
//
#include <hip/hip_runtime.h>
#include <stdint.h>

#define T_TOK 4096
#define DIN   2048
#define DQ    2048
#define DKV   2048
#define NOUT  (DQ + 2*DKV)         /* 6144 */
#define NA    4
#define RLORA 16
#define BM    256
#define BN    256
#define MPAD  (T_TOK + NA*BM)      /* 5120 */
#define MTILES (MPAD/BM)           /* 20 */
#define KX    (DIN + 64)           /* 2112 = 33 * 64 */
#define NT    (KX/64)              /* 33 K-tiles of 64 */
#define KSPLIT 16
#define NTBLK (NOUT/BN)            /* 24 */
#define NWG   (MTILES*NTBLK)       /* 480 */

typedef unsigned short u16;
typedef __attribute__((ext_vector_type(8))) short short8;
typedef __attribute__((ext_vector_type(8))) u16 u16x8;
typedef __attribute__((ext_vector_type(4))) float f32x4;

__device__ __forceinline__ u16 f2bf(float f) {
  uint32_t u = __float_as_uint(f);
  u = (u + 0x7FFFu + ((u >> 16) & 1u)) >> 16;
  return (u16)u;
}
__device__ __forceinline__ float bf2f(u16 u) {
  return __uint_as_float(((uint32_t)u) << 16);
}

typedef __attribute__((address_space(3))) void lds_void;
typedef __attribute__((address_space(1))) void glb_void;

__device__ __forceinline__ void gl_lds16(const void* g, void* l) {
  __builtin_amdgcn_global_load_lds((const glb_void*)(uintptr_t)g,
                                   (lds_void*)(uint32_t)(uintptr_t)l, 16, 0, 0);
}

// ---------------------------------------------------------------------------
// Kernel 1: stable counting sort of tokens by adapter, padded to BM multiples.
// tileAdapter[t] = adapter, or -1 for fully-empty tiles.
// ---------------------------------------------------------------------------
__global__ void prep_kernel(const int* __restrict__ widx,
                            int* __restrict__ tok,
                            int* __restrict__ tileAdapter) {
  __shared__ int cnt[256][NA];
  __shared__ int total[NA];
  __shared__ int pad_off[NA];
  const int tid = threadIdx.x;
  const int CH = T_TOK / 256;  // 16
  const int base = tid * CH;
  int c[NA] = {0, 0, 0, 0};
  for (int i = 0; i < CH; i++) c[widx[base + i]]++;
  for (int a = 0; a < NA; a++) cnt[tid][a] = c[a];
  __syncthreads();
  if (tid < NA) {
    int s = 0;
    for (int i = 0; i < 256; i++) { int v = cnt[i][tid]; cnt[i][tid] = s; s += v; }
    total[tid] = s;
  }
  __syncthreads();
  if (tid == 0) {
    int off = 0;
    for (int a = 0; a < NA; a++) {
      pad_off[a] = off;
      int ntile = (total[a] + BM - 1) / BM;
      for (int tl = 0; tl < ntile; tl++) tileAdapter[off / BM + tl] = a;
      off += ntile * BM;
    }
    for (int tl = off / BM; tl < MTILES; tl++) tileAdapter[tl] = -1;
  }
  __syncthreads();
  for (int i = tid; i < MPAD; i += 256) tok[i] = -1;
  __syncthreads();
  int myoff[NA];
  for (int a = 0; a < NA; a++) myoff[a] = pad_off[a] + cnt[tid][a];
  for (int i = 0; i < CH; i++) {
    int a = widx[base + i];
    tok[myoff[a]++] = base + i;
  }
}

// ---------------------------------------------------------------------------
// Kernel 2: gather x rows into sorted order -> bf16 (cols 0..2047 of Xg).
// ---------------------------------------------------------------------------
__global__ void gather_kernel(const float* __restrict__ x,
                              const int* __restrict__ tok,
                              u16* __restrict__ Xg) {
  const int row = blockIdx.x;
  const int t = tok[row];
  const int tid = threadIdx.x;
  u16x8* dst = (u16x8*)(Xg + (size_t)row * KX);
  if (t < 0) {
    u16x8 z = {0, 0, 0, 0, 0, 0, 0, 0};
    dst[tid] = z;
    return;
  }
  const f32x4* src = (const f32x4*)(x + (size_t)t * DIN);
  f32x4 v0 = src[tid * 2];
  f32x4 v1 = src[tid * 2 + 1];
  u16x8 o;
  o[0] = f2bf(v0[0]); o[1] = f2bf(v0[1]); o[2] = f2bf(v0[2]); o[3] = f2bf(v0[3]);
  o[4] = f2bf(v1[0]); o[5] = f2bf(v1[1]); o[6] = f2bf(v1[2]); o[7] = f2bf(v1[3]);
  dst[tid] = o;
}

// ---------------------------------------------------------------------------
// Kernel 3: Xa partials.  Xa = Xg[:, :2048] @ A_qkv[a]  ([M x 48]).
// Block handles 128 rows; grid (MPAD/128, KSPLIT).
// ---------------------------------------------------------------------------
__global__ __launch_bounds__(256) void xa_partial_kernel(
    const u16* __restrict__ Xg, const float* __restrict__ A_qkv,
    const int* __restrict__ tileAdapter, float* __restrict__ Ppart) {
  const int ks = blockIdx.y;
  const int ad = tileAdapter[blockIdx.x >> 1];
  const int a = ad < 0 ? 0 : ad;
  const int kb = ks * (DIN / KSPLIT);   // 128-wide K slice
  const int tid = threadIdx.x;
  const int rg = tid >> 2;              // 0..63
  const int jg = tid & 3;               // 0..3
  const int r0 = blockIdx.x * 128 + rg * 2;
  const int j0 = jg * 12;
  __shared__ float ldsA[64][56];
  float acc[2][12];
  #pragma unroll
  for (int r = 0; r < 2; r++)
    #pragma unroll
    for (int j = 0; j < 12; j++) acc[r][j] = 0.f;

  for (int kc = 0; kc < 2; kc++) {
    const int kbase = kb + kc * 64;
    for (int i = tid; i < 64 * 48; i += 256) {
      int kk = i / 48, j = i - kk * 48;
      ldsA[kk][j] = A_qkv[((size_t)a * DIN + kbase + kk) * (3 * RLORA) + j];
    }
    __syncthreads();
    u16x8 xr[2][8];
    #pragma unroll
    for (int r = 0; r < 2; r++)
      #pragma unroll
      for (int q = 0; q < 8; q++)
        xr[r][q] = *(const u16x8*)(Xg + (size_t)(r0 + r) * KX + kbase + q * 8);
    #pragma unroll
    for (int q = 0; q < 8; q++) {
      #pragma unroll
      for (int e = 0; e < 8; e++) {
        const int kk = q * 8 + e;
        f32x4 a0 = *(const f32x4*)&ldsA[kk][j0];
        f32x4 a1 = *(const f32x4*)&ldsA[kk][j0 + 4];
        f32x4 a2 = *(const f32x4*)&ldsA[kk][j0 + 8];
        float x0 = bf2f(xr[0][q][e]);
        float x1 = bf2f(xr[1][q][e]);
        #pragma unroll
        for (int c = 0; c < 4; c++) {
          acc[0][c]     += x0 * a0[c];  acc[1][c]     += x1 * a0[c];
          acc[0][4 + c] += x0 * a1[c];  acc[1][4 + c] += x1 * a1[c];
          acc[0][8 + c] += x0 * a2[c];  acc[1][8 + c] += x1 * a2[c];
        }
      }
    }
    __syncthreads();
  }
  #pragma unroll
  for (int r = 0; r < 2; r++)
    #pragma unroll
    for (int j = 0; j < 12; j++)
      Ppart[((size_t)ks * MPAD + r0 + r) * 48 + j0 + j] = acc[r][j];
}

// ---------------------------------------------------------------------------
// Kernel 4: reduce partials -> bf16 into Xg cols 2048..2111 (j>=48 zero).
// ---------------------------------------------------------------------------
__global__ void xa_reduce_kernel(const float* __restrict__ Ppart,
                                 u16* __restrict__ Xg) {
  const int gid = blockIdx.x * 256 + threadIdx.x;
  const int row = gid >> 6, j = gid & 63;
  float s = 0.f;
  if (j < 48) {
    #pragma unroll
    for (int sp = 0; sp < KSPLIT; sp++)
      s += Ppart[((size_t)sp * MPAD + row) * 48 + j];
  }
  Xg[(size_t)row * KX + DIN + j] = f2bf(s);
}

// ---------------------------------------------------------------------------
// Kernel 5: Weff[a][n][k] = W_base[n][k] + Delta[a][k][n], bf16, k<2048.
// ---------------------------------------------------------------------------
__global__ __launch_bounds__(256) void weff2_kernel(
    const float* __restrict__ W_base,
    const float* __restrict__ DW_q, const float* __restrict__ DW_kv,
    u16* __restrict__ Weff) {
  const int k0 = blockIdx.x * 64;
  const int n0 = blockIdx.y * 64;
  const int tid = threadIdx.x;
  const int k8 = (tid & 7) * 8;
  __shared__ float ldsD[64][65];

  f32x4 wb[2][2];
  #pragma unroll
  for (int h = 0; h < 2; h++) {
    const int nn = h * 32 + (tid >> 3);
    const float* p = W_base + (size_t)(n0 + nn) * DIN + k0 + k8;
    wb[h][0] = *(const f32x4*)p;
    wb[h][1] = *(const f32x4*)(p + 4);
  }

  const int ldD  = (n0 < DQ) ? DQ : 2 * DKV;
  const int ncol = (n0 < DQ) ? n0 : n0 - DQ;

  for (int a = 0; a < NA; a++) {
    const float* Dp = (n0 < DQ)
        ? DW_q  + (size_t)a * DIN * DQ + ncol
        : DW_kv + (size_t)a * DIN * (2 * DKV) + ncol;
    for (int i = tid; i < 64 * 64; i += 256) {
      int kk = i >> 6, nn2 = i & 63;
      ldsD[kk][nn2] = Dp[(size_t)(k0 + kk) * ldD + nn2];
    }
    __syncthreads();
    #pragma unroll
    for (int h = 0; h < 2; h++) {
      const int nn = h * 32 + (tid >> 3);
      u16x8 o;
      #pragma unroll
      for (int j = 0; j < 8; j++)
        o[j] = f2bf(wb[h][j >> 2][j & 3] + ldsD[k8 + j][nn]);
      *(u16x8*)(Weff + ((size_t)a * NOUT + n0 + nn) * KX + k0 + k8) = o;
    }
    __syncthreads();
  }
}

// ---------------------------------------------------------------------------
// Kernel 6: fill Weff[a][n][2048..2111] with scattered B (LoRA slots).
// ---------------------------------------------------------------------------
__global__ void wslots_kernel(const float* __restrict__ B_q,
                              const float* __restrict__ B_kv,
                              u16* __restrict__ Weff) {
  const int a = blockIdx.y;
  const int n = blockIdx.x * 256 + threadIdx.x;
  const int seg = n >> 11;   // 0=q, 1=k, 2=v
  u16 vals[64];
  #pragma unroll
  for (int j = 0; j < 64; j++) vals[j] = 0;
  if (seg == 0) {
    const float* Bp = B_q + ((size_t)a * RLORA) * DQ + n;
    for (int r = 0; r < RLORA; r++) vals[r] = f2bf(Bp[(size_t)r * DQ]);
  } else {
    const float* Bp = B_kv + ((size_t)a * RLORA) * (2 * DKV) + (n - DQ);
    for (int r = 0; r < RLORA; r++)
      vals[seg * RLORA + r] = f2bf(Bp[(size_t)r * (2 * DKV)]);
  }
  u16* dst = Weff + ((size_t)a * NOUT + n) * KX + DIN;
  #pragma unroll
  for (int v = 0; v < 8; v++) *(u16x8*)(dst + v * 8) = *(u16x8*)(vals + v * 8);
}

// ---------------------------------------------------------------------------
// Kernel 7: grouped GEMM, 256x256 tile, BK=64, 8 waves (2Mx4N), 8-phase
// schedule with counted waits, XOR-swizzled LDS, XCD-swizzled grid.
// out[tok[m]] = Xg[m] @ Weff[a]^T  (bf16 MFMA 16x16x32)
// ---------------------------------------------------------------------------
#define BAR    asm volatile("s_barrier" ::: "memory")
#define WAITV0 asm volatile("s_waitcnt vmcnt(0)" ::: "memory")

#define DSREAD(base, row, cb) \
  (*(const short8*)((const char*)(base) + ((row) * 128 + (cb))))

#define LOAD_A(Al, mh) { \
  _Pragma("unroll") for (int mi2 = 0; mi2 < 4; ++mi2) { \
    const int ar = wm * 128 + ((mh) * 4 + mi2) * 16 + fr; \
    af[mi2][0] = DSREAD(Al, ar, ksl ^ sw); \
    af[mi2][1] = DSREAD(Al, ar, (64 + ksl) ^ sw); \
  } }

#define LOAD_B(Bl, nh) { \
  _Pragma("unroll") for (int ni2 = 0; ni2 < 2; ++ni2) { \
    const int br = wn * 64 + ((nh) * 2 + ni2) * 16 + fr; \
    bf[ni2][0] = DSREAD(Bl, br, ksl ^ sw); \
    bf[ni2][1] = DSREAD(Bl, br, (64 + ksl) ^ sw); \
  } }

#define MFMA16(mh, nh) { \
  __builtin_amdgcn_s_setprio(1); \
  _Pragma("unroll") for (int mi2 = 0; mi2 < 4; ++mi2) \
  _Pragma("unroll") for (int ni2 = 0; ni2 < 2; ++ni2) { \
    acc[(mh)*4+mi2][(nh)*2+ni2] = __builtin_amdgcn_mfma_f32_16x16x32_bf16( \
        af[mi2][0], bf[ni2][0], acc[(mh)*4+mi2][(nh)*2+ni2], 0, 0, 0); \
    acc[(mh)*4+mi2][(nh)*2+ni2] = __builtin_amdgcn_mfma_f32_16x16x32_bf16( \
        af[mi2][1], bf[ni2][1], acc[(mh)*4+mi2][(nh)*2+ni2], 0, 0, 0); \
  } \
  __builtin_amdgcn_s_setprio(0); }

#define STAGE_T(ldsbase, gptr, ktE) { \
  _Pragma("unroll") for (int j = 0; j < 4; ++j) \
    gl_lds16((gptr) + (size_t)(j * 64) * KX + (ktE), \
             (u16*)(ldsbase) + (size_t)(j * 512 + tid) * 8); }

__global__ __launch_bounds__(512, 2) void gemm256_kernel(
    const u16* __restrict__ Xg, const u16* __restrict__ Weff,
    const int* __restrict__ tok, const int* __restrict__ tileAdapter,
    float* __restrict__ out) {
  __shared__ __align__(16) u16 As[2][256 * 64];
  __shared__ __align__(16) u16 Bs[2][256 * 64];

  // bijective XCD swizzle: 480 blocks = 60 per XCD
  const int bid = blockIdx.x;
  const int wg = (bid & 7) * (NWG / 8) + (bid >> 3);
  const int mt = wg % MTILES, nt = wg / MTILES;
  const int a = tileAdapter[mt];
  if (a < 0) return;  // fully-padded tile
  const int m0 = mt * BM, n0 = nt * BN;
  const u16* Ag = Xg + (size_t)m0 * KX;
  const u16* Bg = Weff + (size_t)a * NOUT * KX + (size_t)n0 * KX;

  const int tid = threadIdx.x;
  const int l = tid & 63, w = tid >> 6;
  const int wm = w >> 2, wn = w & 3;

  // ds_read lane constants
  const int fr = l & 15;
  const int ksl = (l >> 4) << 4;     // 0,16,32,48 bytes within a 64B k-slice
  const int sw = (l & 7) << 4;       // XOR swizzle (row&7)<<4; row&7 == l&7

  // staging lane constants (pre-swizzled global source)
  const int srow = tid >> 3;                                   // 0..63
  const int scol = (((tid & 7) * 16) ^ ((srow & 7) << 4)) >> 1; // elements
  const u16* gAs = Ag + (size_t)srow * KX + scol;
  const u16* gBs = Bg + (size_t)srow * KX + scol;

  u16* const A0w = &As[0][0];  u16* const A1w = &As[1][0];
  u16* const B0w = &Bs[0][0];  u16* const B1w = &Bs[1][0];
  const u16* const A0r = A0w;  const u16* const A1r = A1w;
  const u16* const B0r = B0w;  const u16* const B1r = B1w;

  f32x4 acc[8][4];
  #pragma unroll
  for (int i = 0; i < 8; i++)
    #pragma unroll
    for (int j = 0; j < 4; j++) acc[i][j] = (f32x4){0.f, 0.f, 0.f, 0.f};

  short8 af[4][2], bf[2][2];

  // prologue: stage tile 0 into buf0
  STAGE_T(A0w, gAs, 0);
  STAGE_T(B0w, gBs, 0);
  WAITV0;
  BAR;

  for (int pair = 0; pair < NT / 2; ++pair) {   // 16 pairs: tiles 0..31
    const int ktA = (2 * pair + 1) * 64;  // staged in ph1-2 -> buf1
    const int ktB = (2 * pair + 2) * 64;  // staged in ph5-6 -> buf0
    // ---- tile 2p in buf0 ----
    LOAD_A(A0r, 0); LOAD_B(B0r, 0); STAGE_T(A1w, gAs, ktA); BAR; MFMA16(0, 0); BAR;
    LOAD_B(B0r, 1);                 STAGE_T(B1w, gBs, ktA); BAR; MFMA16(0, 1); BAR;
    LOAD_A(A0r, 1); LOAD_B(B0r, 0);                         BAR; MFMA16(1, 0); BAR;
    LOAD_B(B0r, 1);                                         BAR; MFMA16(1, 1);
    WAITV0; BAR;
    // ---- tile 2p+1 in buf1 ----
    LOAD_A(A1r, 0); LOAD_B(B1r, 0); STAGE_T(A0w, gAs, ktB); BAR; MFMA16(0, 0); BAR;
    LOAD_B(B1r, 1);                 STAGE_T(B0w, gBs, ktB); BAR; MFMA16(0, 1); BAR;
    LOAD_A(A1r, 1); LOAD_B(B1r, 0);                         BAR; MFMA16(1, 0); BAR;
    LOAD_B(B1r, 1);                                         BAR; MFMA16(1, 1);
    WAITV0; BAR;
  }
  // epilogue K-tile 32 (already in buf0, waited)
  LOAD_A(A0r, 0); LOAD_B(B0r, 0); BAR; MFMA16(0, 0); BAR;
  LOAD_B(B0r, 1);                 BAR; MFMA16(0, 1); BAR;
  LOAD_A(A0r, 1); LOAD_B(B0r, 0); BAR; MFMA16(1, 0); BAR;
  LOAD_B(B0r, 1);                 BAR; MFMA16(1, 1);

  // C-write: scatter rows via tok
  #pragma unroll
  for (int mi = 0; mi < 8; ++mi) {
    const int rb = m0 + wm * 128 + mi * 16 + ((l >> 4) << 2);
    int tt[4];
    #pragma unroll
    for (int reg = 0; reg < 4; ++reg) tt[reg] = tok[rb + reg];
    #pragma unroll
    for (int ni = 0; ni < 4; ++ni) {
      const int col = n0 + wn * 64 + ni * 16 + fr;
      #pragma unroll
      for (int reg = 0; reg < 4; ++reg)
        if (tt[reg] >= 0) out[(size_t)tt[reg] * NOUT + col] = acc[mi][ni][reg];
    }
  }
}

// ---------------------------------------------------------------------------
// Fallback (ws too small): correct fp32 path.
// ---------------------------------------------------------------------------
__global__ void fallback_kernel(const float* __restrict__ x,
                                const float* __restrict__ W_base,
                                const float* __restrict__ A_qkv,
                                const float* __restrict__ B_q,
                                const float* __restrict__ B_kv,
                                const float* __restrict__ DW_q,
                                const float* __restrict__ DW_kv,
                                const int* __restrict__ widx,
                                float* __restrict__ out) {
  const int t = blockIdx.x;
  const int n = blockIdx.y * 256 + threadIdx.x;
  const int a = widx[t];
  __shared__ float xs[DIN];
  __shared__ float ys[3 * RLORA];
  for (int k = threadIdx.x; k < DIN; k += 256) xs[k] = x[(size_t)t * DIN + k];
  __syncthreads();
  if (threadIdx.x < 3 * RLORA) {
    float s = 0.f;
    const float* Ap = A_qkv + (size_t)a * DIN * (3 * RLORA) + threadIdx.x;
    for (int k = 0; k < DIN; k++) s += xs[k] * Ap[(size_t)k * (3 * RLORA)];
    ys[threadIdx.x] = s;
  }
  __syncthreads();
  const float* dcol; int ldD, roff; const float* bcol; int ldB;
  if (n < DQ) {
    dcol = DW_q + (size_t)a * DIN * DQ + n; ldD = DQ; roff = 0;
    bcol = B_q + (size_t)a * RLORA * DQ + n; ldB = DQ;
  } else {
    dcol = DW_kv + (size_t)a * DIN * (2 * DKV) + (n - DQ); ldD = 2 * DKV;
    roff = (n < 2 * DQ) ? RLORA : 2 * RLORA;
    bcol = B_kv + (size_t)a * RLORA * (2 * DKV) + (n - DQ); ldB = 2 * DKV;
  }
  const float* wrow = W_base + (size_t)n * DIN;
  float acc = 0.f;
  for (int k = 0; k < DIN; k++) acc += xs[k] * (wrow[k] + dcol[(size_t)k * ldD]);
  for (int r = 0; r < RLORA; r++) acc += ys[roff + r] * bcol[(size_t)r * ldB];
  out[(size_t)t * NOUT + n] = acc;
}

// ---------------------------------------------------------------------------
extern "C" void kernel_launch(void* const* d_in, const int* in_sizes, int n_in,
                              void* d_out, int out_size, void* d_ws, size_t ws_size,
                              hipStream_t stream) {
  const float* x      = (const float*)d_in[0];
  const float* W_base = (const float*)d_in[1];
  const float* A_qkv  = (const float*)d_in[2];
  const float* B_q    = (const float*)d_in[3];
  const float* B_kv   = (const float*)d_in[4];
  const float* DW_q   = (const float*)d_in[5];
  const float* DW_kv  = (const float*)d_in[6];
  const int*   widx   = (const int*)d_in[7];
  float* out = (float*)d_out;

  const size_t WEFF_BYTES = (size_t)NA * NOUT * KX * sizeof(u16);   // 103.8 MB
  const size_t XG_BYTES   = (size_t)MPAD * KX * sizeof(u16);        // 21.6 MB
  const size_t TOK_BYTES  = (size_t)MPAD * sizeof(int);
  const size_t TILE_BYTES = (size_t)MTILES * sizeof(int);
  const size_t need = WEFF_BYTES + XG_BYTES + TOK_BYTES + TILE_BYTES;

  if (ws_size < need) {
    fallback_kernel<<<dim3(T_TOK, NOUT / 256), 256, 0, stream>>>(
        x, W_base, A_qkv, B_q, B_kv, DW_q, DW_kv, widx, out);
    return;
  }

  char* ws = (char*)d_ws;
  u16* Weff = (u16*)ws;
  u16* Xg   = (u16*)(ws + WEFF_BYTES);
  int* tok  = (int*)(ws + WEFF_BYTES + XG_BYTES);
  int* tileAdapter = tok + MPAD;
  // Xa partial buffer aliases the Weff region (consumed by xa_reduce BEFORE
  // weff2 writes Weff; stream-serialized). 16*5120*48*4 = 15.7 MB < 103.8 MB.
  float* Ppart = (float*)ws;

  prep_kernel<<<1, 256, 0, stream>>>(widx, tok, tileAdapter);
  gather_kernel<<<MPAD, 256, 0, stream>>>(x, tok, Xg);
  xa_partial_kernel<<<dim3(MPAD / 128, KSPLIT), 256, 0, stream>>>(
      Xg, A_qkv, tileAdapter, Ppart);
  xa_reduce_kernel<<<MPAD * 64 / 256, 256, 0, stream>>>(Ppart, Xg);
  weff2_kernel<<<dim3(DIN / 64, NOUT / 64), 256, 0, stream>>>(
      W_base, DW_q, DW_kv, Weff);
  wslots_kernel<<<dim3(NOUT / 256, NA), 256, 0, stream>>>(B_q, B_kv, Weff);
  gemm256_kernel<<<dim3(NWG), 512, 0, stream>>>(
      Xg, Weff, tok, tileAdapter, out);
}

// Round 4
// 262.751 us; speedup vs baseline: 2.0805x; 1.0146x over previous
//
#include <hip/hip_runtime.h>
#include <stdint.h>

#define T_TOK 4096
#define DIN   2048
#define DQ    2048
#define DKV   2048
#define NOUT  (DQ + 2*DKV)         /* 6144 */
#define NA    4
#define RLORA 16
#define BM    256
#define BN    256
#define MPAD  (T_TOK + NA*BM)      /* 5120 */
#define MTILES (MPAD/BM)           /* 20 */
#define KX    (DIN + 64)           /* 2112 */
#define NKT   (KX/32)              /* 66 K-tiles of 32 */
#define KSPLIT 16
#define NTBLK (NOUT/BN)            /* 24 */
#define NWG   (MTILES*NTBLK)       /* 480 */

typedef unsigned short u16;
typedef __attribute__((ext_vector_type(8))) short short8;
typedef __attribute__((ext_vector_type(8))) u16 u16x8;
typedef __attribute__((ext_vector_type(4))) float f32x4;

__device__ __forceinline__ u16 f2bf(float f) {
  uint32_t u = __float_as_uint(f);
  u = (u + 0x7FFFu + ((u >> 16) & 1u)) >> 16;
  return (u16)u;
}
__device__ __forceinline__ float bf2f(u16 u) {
  return __uint_as_float(((uint32_t)u) << 16);
}

typedef __attribute__((address_space(3))) void lds_void;
typedef __attribute__((address_space(1))) void glb_void;

__device__ __forceinline__ void gl_lds16(const void* g, void* l) {
  __builtin_amdgcn_global_load_lds((const glb_void*)(uintptr_t)g,
                                   (lds_void*)(uint32_t)(uintptr_t)l, 16, 0, 0);
}

// ---------------------------------------------------------------------------
// Kernel 1: stable counting sort of tokens by adapter, padded to BM multiples.
// ---------------------------------------------------------------------------
__global__ void prep_kernel(const int* __restrict__ widx,
                            int* __restrict__ tok,
                            int* __restrict__ tileAdapter) {
  __shared__ int cnt[256][NA];
  __shared__ int total[NA];
  __shared__ int pad_off[NA];
  const int tid = threadIdx.x;
  const int CH = T_TOK / 256;  // 16
  const int base = tid * CH;
  int c[NA] = {0, 0, 0, 0};
  for (int i = 0; i < CH; i++) c[widx[base + i]]++;
  for (int a = 0; a < NA; a++) cnt[tid][a] = c[a];
  __syncthreads();
  if (tid < NA) {
    int s = 0;
    for (int i = 0; i < 256; i++) { int v = cnt[i][tid]; cnt[i][tid] = s; s += v; }
    total[tid] = s;
  }
  __syncthreads();
  if (tid == 0) {
    int off = 0;
    for (int a = 0; a < NA; a++) {
      pad_off[a] = off;
      int ntile = (total[a] + BM - 1) / BM;
      for (int tl = 0; tl < ntile; tl++) tileAdapter[off / BM + tl] = a;
      off += ntile * BM;
    }
    for (int tl = off / BM; tl < MTILES; tl++) tileAdapter[tl] = -1;
  }
  __syncthreads();
  for (int i = tid; i < MPAD; i += 256) tok[i] = -1;
  __syncthreads();
  int myoff[NA];
  for (int a = 0; a < NA; a++) myoff[a] = pad_off[a] + cnt[tid][a];
  for (int i = 0; i < CH; i++) {
    int a = widx[base + i];
    tok[myoff[a]++] = base + i;
  }
}

// ---------------------------------------------------------------------------
// Kernel 2: gather x rows into sorted order -> bf16 (cols 0..2047 of Xg).
// ---------------------------------------------------------------------------
__global__ void gather_kernel(const float* __restrict__ x,
                              const int* __restrict__ tok,
                              u16* __restrict__ Xg) {
  const int row = blockIdx.x;
  const int t = tok[row];
  const int tid = threadIdx.x;
  u16x8* dst = (u16x8*)(Xg + (size_t)row * KX);
  if (t < 0) {
    u16x8 z = {0, 0, 0, 0, 0, 0, 0, 0};
    dst[tid] = z;
    return;
  }
  const f32x4* src = (const f32x4*)(x + (size_t)t * DIN);
  f32x4 v0 = src[tid * 2];
  f32x4 v1 = src[tid * 2 + 1];
  u16x8 o;
  o[0] = f2bf(v0[0]); o[1] = f2bf(v0[1]); o[2] = f2bf(v0[2]); o[3] = f2bf(v0[3]);
  o[4] = f2bf(v1[0]); o[5] = f2bf(v1[1]); o[6] = f2bf(v1[2]); o[7] = f2bf(v1[3]);
  dst[tid] = o;
}

// ---------------------------------------------------------------------------
// Kernel 3: Xa partials.  Xa = Xg[:, :2048] @ A_qkv[a]  ([M x 48]).
// ---------------------------------------------------------------------------
__global__ __launch_bounds__(256) void xa_partial_kernel(
    const u16* __restrict__ Xg, const float* __restrict__ A_qkv,
    const int* __restrict__ tileAdapter, float* __restrict__ Ppart) {
  const int ks = blockIdx.y;
  const int ad = tileAdapter[blockIdx.x >> 1];
  const int a = ad < 0 ? 0 : ad;
  const int kb = ks * (DIN / KSPLIT);
  const int tid = threadIdx.x;
  const int rg = tid >> 2;
  const int jg = tid & 3;
  const int r0 = blockIdx.x * 128 + rg * 2;
  const int j0 = jg * 12;
  __shared__ float ldsA[64][56];
  float acc[2][12];
  #pragma unroll
  for (int r = 0; r < 2; r++)
    #pragma unroll
    for (int j = 0; j < 12; j++) acc[r][j] = 0.f;

  for (int kc = 0; kc < 2; kc++) {
    const int kbase = kb + kc * 64;
    for (int i = tid; i < 64 * 48; i += 256) {
      int kk = i / 48, j = i - kk * 48;
      ldsA[kk][j] = A_qkv[((size_t)a * DIN + kbase + kk) * (3 * RLORA) + j];
    }
    __syncthreads();
    u16x8 xr[2][8];
    #pragma unroll
    for (int r = 0; r < 2; r++)
      #pragma unroll
      for (int q = 0; q < 8; q++)
        xr[r][q] = *(const u16x8*)(Xg + (size_t)(r0 + r) * KX + kbase + q * 8);
    #pragma unroll
    for (int q = 0; q < 8; q++) {
      #pragma unroll
      for (int e = 0; e < 8; e++) {
        const int kk = q * 8 + e;
        f32x4 a0 = *(const f32x4*)&ldsA[kk][j0];
        f32x4 a1 = *(const f32x4*)&ldsA[kk][j0 + 4];
        f32x4 a2 = *(const f32x4*)&ldsA[kk][j0 + 8];
        float x0 = bf2f(xr[0][q][e]);
        float x1 = bf2f(xr[1][q][e]);
        #pragma unroll
        for (int c = 0; c < 4; c++) {
          acc[0][c]     += x0 * a0[c];  acc[1][c]     += x1 * a0[c];
          acc[0][4 + c] += x0 * a1[c];  acc[1][4 + c] += x1 * a1[c];
          acc[0][8 + c] += x0 * a2[c];  acc[1][8 + c] += x1 * a2[c];
        }
      }
    }
    __syncthreads();
  }
  #pragma unroll
  for (int r = 0; r < 2; r++)
    #pragma unroll
    for (int j = 0; j < 12; j++)
      Ppart[((size_t)ks * MPAD + r0 + r) * 48 + j0 + j] = acc[r][j];
}

// ---------------------------------------------------------------------------
// Kernel 4: reduce partials -> bf16 into Xg cols 2048..2111 (j>=48 zero).
// ---------------------------------------------------------------------------
__global__ void xa_reduce_kernel(const float* __restrict__ Ppart,
                                 u16* __restrict__ Xg) {
  const int gid = blockIdx.x * 256 + threadIdx.x;
  const int row = gid >> 6, j = gid & 63;
  float s = 0.f;
  if (j < 48) {
    #pragma unroll
    for (int sp = 0; sp < KSPLIT; sp++)
      s += Ppart[((size_t)sp * MPAD + row) * 48 + j];
  }
  Xg[(size_t)row * KX + DIN + j] = f2bf(s);
}

// ---------------------------------------------------------------------------
// Kernel 5: Weff[a][n][k] = W_base[n][k] + Delta[a][k][n], bf16, k<2048.
// ---------------------------------------------------------------------------
__global__ __launch_bounds__(256) void weff2_kernel(
    const float* __restrict__ W_base,
    const float* __restrict__ DW_q, const float* __restrict__ DW_kv,
    u16* __restrict__ Weff) {
  const int k0 = blockIdx.x * 64;
  const int n0 = blockIdx.y * 64;
  const int tid = threadIdx.x;
  const int k8 = (tid & 7) * 8;
  __shared__ float ldsD[64][65];

  f32x4 wb[2][2];
  #pragma unroll
  for (int h = 0; h < 2; h++) {
    const int nn = h * 32 + (tid >> 3);
    const float* p = W_base + (size_t)(n0 + nn) * DIN + k0 + k8;
    wb[h][0] = *(const f32x4*)p;
    wb[h][1] = *(const f32x4*)(p + 4);
  }

  const int ldD  = (n0 < DQ) ? DQ : 2 * DKV;
  const int ncol = (n0 < DQ) ? n0 : n0 - DQ;

  for (int a = 0; a < NA; a++) {
    const float* Dp = (n0 < DQ)
        ? DW_q  + (size_t)a * DIN * DQ + ncol
        : DW_kv + (size_t)a * DIN * (2 * DKV) + ncol;
    for (int i = tid; i < 64 * 64; i += 256) {
      int kk = i >> 6, nn2 = i & 63;
      ldsD[kk][nn2] = Dp[(size_t)(k0 + kk) * ldD + nn2];
    }
    __syncthreads();
    #pragma unroll
    for (int h = 0; h < 2; h++) {
      const int nn = h * 32 + (tid >> 3);
      u16x8 o;
      #pragma unroll
      for (int j = 0; j < 8; j++)
        o[j] = f2bf(wb[h][j >> 2][j & 3] + ldsD[k8 + j][nn]);
      *(u16x8*)(Weff + ((size_t)a * NOUT + n0 + nn) * KX + k0 + k8) = o;
    }
    __syncthreads();
  }
}

// ---------------------------------------------------------------------------
// Kernel 6: fill Weff[a][n][2048..2111] with scattered B (LoRA slots).
// ---------------------------------------------------------------------------
__global__ void wslots_kernel(const float* __restrict__ B_q,
                              const float* __restrict__ B_kv,
                              u16* __restrict__ Weff) {
  const int a = blockIdx.y;
  const int n = blockIdx.x * 256 + threadIdx.x;
  const int seg = n >> 11;   // 0=q, 1=k, 2=v
  u16 vals[64];
  #pragma unroll
  for (int j = 0; j < 64; j++) vals[j] = 0;
  if (seg == 0) {
    const float* Bp = B_q + ((size_t)a * RLORA) * DQ + n;
    #pragma unroll
    for (int r = 0; r < RLORA; r++) vals[r] = f2bf(Bp[(size_t)r * DQ]);
  } else if (seg == 1) {
    const float* Bp = B_kv + ((size_t)a * RLORA) * (2 * DKV) + (n - DQ);
    #pragma unroll
    for (int r = 0; r < RLORA; r++) vals[RLORA + r] = f2bf(Bp[(size_t)r * (2 * DKV)]);
  } else {
    const float* Bp = B_kv + ((size_t)a * RLORA) * (2 * DKV) + (n - DQ);
    #pragma unroll
    for (int r = 0; r < RLORA; r++) vals[2 * RLORA + r] = f2bf(Bp[(size_t)r * (2 * DKV)]);
  }
  u16* dst = Weff + ((size_t)a * NOUT + n) * KX + DIN;
  #pragma unroll
  for (int v = 0; v < 8; v++) *(u16x8*)(dst + v * 8) = *(u16x8*)(vals + v * 8);
}

// ---------------------------------------------------------------------------
// Kernel 7: grouped GEMM, 256x256 tile, BK=32, 8 waves (2Mx4N).
// 4-deep circular LDS pipeline, counted vmcnt (8/4/0), 1 barrier per K-tile.
// out[tok[m]] = Xg[m] @ Weff[a]^T  (bf16 MFMA 16x16x32)
// ---------------------------------------------------------------------------
#define BAR      asm volatile("s_barrier" ::: "memory")
#define WAITV(n) asm volatile("s_waitcnt vmcnt(" #n ")" ::: "memory")

// Stage K-tile t (32 cols) of A and B into buffer b. 4 loads/thread.
// LDS row = 64B (32 bf16); source column pre-swizzled: chunk ^= (row>>1)&3.
#define STAGE(b, t) { \
  const u16* gA_ = gAs + (size_t)(t) * 32; \
  const u16* gB_ = gBs + (size_t)(t) * 32; \
  u16* lA_ = &lds[b][0][0] + tid * 8; \
  u16* lB_ = &lds[b][1][0] + tid * 8; \
  gl_lds16(gA_, lA_); \
  gl_lds16(gA_ + (size_t)128 * KX, lA_ + 4096); \
  gl_lds16(gB_, lB_); \
  gl_lds16(gB_ + (size_t)128 * KX, lB_ + 4096); \
}

#define COMPUTE(b) { \
  const char* Ab = (const char*)&lds[b][0][0]; \
  const char* Bb = (const char*)&lds[b][1][0]; \
  short8 af[8], bfr[4]; \
  _Pragma("unroll") for (int mi = 0; mi < 8; ++mi) \
    af[mi] = *(const short8*)(Ab + (wm * 128 + mi * 16) * 64 + laneoff); \
  _Pragma("unroll") for (int ni = 0; ni < 4; ++ni) \
    bfr[ni] = *(const short8*)(Bb + (wn * 64 + ni * 16) * 64 + laneoff); \
  __builtin_amdgcn_s_setprio(1); \
  _Pragma("unroll") for (int mi = 0; mi < 8; ++mi) \
  _Pragma("unroll") for (int ni = 0; ni < 4; ++ni) \
    acc[mi][ni] = __builtin_amdgcn_mfma_f32_16x16x32_bf16( \
        af[mi], bfr[ni], acc[mi][ni], 0, 0, 0); \
  __builtin_amdgcn_s_setprio(0); \
}

__global__ __launch_bounds__(512, 2) void gemm256_kernel(
    const u16* __restrict__ Xg, const u16* __restrict__ Weff,
    const int* __restrict__ tok, const int* __restrict__ tileAdapter,
    float* __restrict__ out) {
  __shared__ __align__(16) u16 lds[4][2][256 * 32];   // 128 KiB

  // bijective XCD swizzle: 480 blocks = 60 per XCD
  const int bid = blockIdx.x;
  const int wg = (bid & 7) * (NWG / 8) + (bid >> 3);
  const int mt = wg % MTILES, nt = wg / MTILES;
  const int a = tileAdapter[mt];
  if (a < 0) return;  // fully-padded tile (block-uniform exit)
  const int m0 = mt * BM, n0 = nt * BN;

  const int tid = threadIdx.x;
  const int l = tid & 63, w = tid >> 6;
  const int wm = w >> 2, wn = w & 3;
  const int fr = l & 15;
  // read-side swizzled lane offset: row fr, k-chunk (l>>4) ^ ((fr>>1)&3)
  const int laneoff = fr * 64 + ((((l >> 4) ^ ((fr >> 1) & 3))) << 4);

  // staging source (pre-swizzled column): thread covers row tid>>2, chunk tid&3
  const int srow = tid >> 2;
  const int scol = (((tid & 3) ^ ((tid >> 3) & 3))) * 8;
  const u16* gAs = Xg + (size_t)(m0 + srow) * KX + scol;
  const u16* gBs = Weff + ((size_t)a * NOUT + n0 + srow) * KX + scol;

  f32x4 acc[8][4];
  #pragma unroll
  for (int i = 0; i < 8; i++)
    #pragma unroll
    for (int j = 0; j < 4; j++) acc[i][j] = (f32x4){0.f, 0.f, 0.f, 0.f};

  // prologue: stage tiles 0,1,2 (12 loads in flight)
  STAGE(0, 0);
  STAGE(1, 1);
  STAGE(2, 2);

  for (int i = 0; i < NKT - 3; ++i) {
    WAITV(8);              // tile i's 4 loads landed (8 newer stay in flight)
    BAR;                   // all waves' tile-i data visible; buf[(i+3)&3] free
    STAGE((i + 3) & 3, i + 3);
    COMPUTE(i & 3);
  }
  // epilogue: tiles NKT-3, NKT-2, NKT-1 (no staging; drain 8 -> 4 -> 0)
  WAITV(8); BAR; COMPUTE((NKT - 3) & 3);
  WAITV(4); BAR; COMPUTE((NKT - 2) & 3);
  WAITV(0); BAR; COMPUTE((NKT - 1) & 3);

  // C-write: scatter rows via tok
  #pragma unroll
  for (int mi = 0; mi < 8; ++mi) {
    const int rb = m0 + wm * 128 + mi * 16 + ((l >> 4) << 2);
    int tt[4];
    #pragma unroll
    for (int reg = 0; reg < 4; ++reg) tt[reg] = tok[rb + reg];
    #pragma unroll
    for (int ni = 0; ni < 4; ++ni) {
      const int col = n0 + wn * 64 + ni * 16 + fr;
      #pragma unroll
      for (int reg = 0; reg < 4; ++reg)
        if (tt[reg] >= 0) out[(size_t)tt[reg] * NOUT + col] = acc[mi][ni][reg];
    }
  }
}

// ---------------------------------------------------------------------------
// Fallback (ws too small): correct fp32 path.
// ---------------------------------------------------------------------------
__global__ void fallback_kernel(const float* __restrict__ x,
                                const float* __restrict__ W_base,
                                const float* __restrict__ A_qkv,
                                const float* __restrict__ B_q,
                                const float* __restrict__ B_kv,
                                const float* __restrict__ DW_q,
                                const float* __restrict__ DW_kv,
                                const int* __restrict__ widx,
                                float* __restrict__ out) {
  const int t = blockIdx.x;
  const int n = blockIdx.y * 256 + threadIdx.x;
  const int a = widx[t];
  __shared__ float xs[DIN];
  __shared__ float ys[3 * RLORA];
  for (int k = threadIdx.x; k < DIN; k += 256) xs[k] = x[(size_t)t * DIN + k];
  __syncthreads();
  if (threadIdx.x < 3 * RLORA) {
    float s = 0.f;
    const float* Ap = A_qkv + (size_t)a * DIN * (3 * RLORA) + threadIdx.x;
    for (int k = 0; k < DIN; k++) s += xs[k] * Ap[(size_t)k * (3 * RLORA)];
    ys[threadIdx.x] = s;
  }
  __syncthreads();
  const float* dcol; int ldD, roff; const float* bcol; int ldB;
  if (n < DQ) {
    dcol = DW_q + (size_t)a * DIN * DQ + n; ldD = DQ; roff = 0;
    bcol = B_q + (size_t)a * RLORA * DQ + n; ldB = DQ;
  } else {
    dcol = DW_kv + (size_t)a * DIN * (2 * DKV) + (n - DQ); ldD = 2 * DKV;
    roff = (n < 2 * DQ) ? RLORA : 2 * RLORA;
    bcol = B_kv + (size_t)a * RLORA * (2 * DKV) + (n - DQ); ldB = 2 * DKV;
  }
  const float* wrow = W_base + (size_t)n * DIN;
  float acc = 0.f;
  for (int k = 0; k < DIN; k++) acc += xs[k] * (wrow[k] + dcol[(size_t)k * ldD]);
  for (int r = 0; r < RLORA; r++) acc += ys[roff + r] * bcol[(size_t)r * ldB];
  out[(size_t)t * NOUT + n] = acc;
}

// ---------------------------------------------------------------------------
extern "C" void kernel_launch(void* const* d_in, const int* in_sizes, int n_in,
                              void* d_out, int out_size, void* d_ws, size_t ws_size,
                              hipStream_t stream) {
  const float* x      = (const float*)d_in[0];
  const float* W_base = (const float*)d_in[1];
  const float* A_qkv  = (const float*)d_in[2];
  const float* B_q    = (const float*)d_in[3];
  const float* B_kv   = (const float*)d_in[4];
  const float* DW_q   = (const float*)d_in[5];
  const float* DW_kv  = (const float*)d_in[6];
  const int*   widx   = (const int*)d_in[7];
  float* out = (float*)d_out;

  const size_t WEFF_BYTES = (size_t)NA * NOUT * KX * sizeof(u16);
  const size_t XG_BYTES   = (size_t)MPAD * KX * sizeof(u16);
  const size_t TOK_BYTES  = (size_t)MPAD * sizeof(int);
  const size_t TILE_BYTES = (size_t)MTILES * sizeof(int);
  const size_t need = WEFF_BYTES + XG_BYTES + TOK_BYTES + TILE_BYTES;

  if (ws_size < need) {
    fallback_kernel<<<dim3(T_TOK, NOUT / 256), 256, 0, stream>>>(
        x, W_base, A_qkv, B_q, B_kv, DW_q, DW_kv, widx, out);
    return;
  }

  char* ws = (char*)d_ws;
  u16* Weff = (u16*)ws;
  u16* Xg   = (u16*)(ws + WEFF_BYTES);
  int* tok  = (int*)(ws + WEFF_BYTES + XG_BYTES);
  int* tileAdapter = tok + MPAD;
  float* Ppart = (float*)ws;   // aliases Weff; consumed before weff2 writes

  prep_kernel<<<1, 256, 0, stream>>>(widx, tok, tileAdapter);
  gather_kernel<<<MPAD, 256, 0, stream>>>(x, tok, Xg);
  xa_partial_kernel<<<dim3(MPAD / 128, KSPLIT), 256, 0, stream>>>(
      Xg, A_qkv, tileAdapter, Ppart);
  xa_reduce_kernel<<<MPAD * 64 / 256, 256, 0, stream>>>(Ppart, Xg);
  weff2_kernel<<<dim3(DIN / 64, NOUT / 64), 256, 0, stream>>>(
      W_base, DW_q, DW_kv, Weff);
  wslots_kernel<<<dim3(NOUT / 256, NA), 256, 0, stream>>>(B_q, B_kv, Weff);
  gemm256_kernel<<<dim3(NWG), 512, 0, stream>>>(
      Xg, Weff, tok, tileAdapter, out);
}

// Round 5
// 248.547 us; speedup vs baseline: 2.1993x; 1.0571x over previous
//
#include <hip/hip_runtime.h>
#include <stdint.h>

#define T_TOK 4096
#define DIN   2048
#define DQ    2048
#define DKV   2048
#define NOUT  (DQ + 2*DKV)         /* 6144 */
#define NA    4
#define RLORA 16
#define BM    256
#define BN    256
#define MPAD  (T_TOK + NA*BM)      /* 5120 */
#define MTILES (MPAD/BM)           /* 20 */
#define KX    (DIN + 64)           /* 2112 = 33*64 */
#define NKT64 (KX/64)              /* 33 K-tiles of 64 */
#define KSPLIT 16
#define NTBLK (NOUT/BN)            /* 24 */
#define NWG   (MTILES*NTBLK)       /* 480 */

typedef unsigned short u16;
typedef __attribute__((ext_vector_type(8))) short short8;
typedef __attribute__((ext_vector_type(8))) u16 u16x8;
typedef __attribute__((ext_vector_type(4))) float f32x4;

__device__ __forceinline__ u16 f2bf(float f) {
  uint32_t u = __float_as_uint(f);
  u = (u + 0x7FFFu + ((u >> 16) & 1u)) >> 16;
  return (u16)u;
}
__device__ __forceinline__ float bf2f(u16 u) {
  return __uint_as_float(((uint32_t)u) << 16);
}

typedef __attribute__((address_space(3))) void lds_void;
typedef __attribute__((address_space(1))) void glb_void;

__device__ __forceinline__ void gl_lds16(const void* g, void* l) {
  __builtin_amdgcn_global_load_lds((const glb_void*)(uintptr_t)g,
                                   (lds_void*)(uint32_t)(uintptr_t)l, 16, 0, 0);
}

// ---------------------------------------------------------------------------
// Kernel 1: stable counting sort of tokens by adapter, padded to BM multiples.
// ---------------------------------------------------------------------------
__global__ void prep_kernel(const int* __restrict__ widx,
                            int* __restrict__ tok,
                            int* __restrict__ tileAdapter) {
  __shared__ int cnt[256][NA];
  __shared__ int total[NA];
  __shared__ int pad_off[NA];
  const int tid = threadIdx.x;
  const int CH = T_TOK / 256;  // 16
  const int base = tid * CH;
  int c[NA] = {0, 0, 0, 0};
  for (int i = 0; i < CH; i++) c[widx[base + i]]++;
  for (int a = 0; a < NA; a++) cnt[tid][a] = c[a];
  __syncthreads();
  if (tid < NA) {
    int s = 0;
    for (int i = 0; i < 256; i++) { int v = cnt[i][tid]; cnt[i][tid] = s; s += v; }
    total[tid] = s;
  }
  __syncthreads();
  if (tid == 0) {
    int off = 0;
    for (int a = 0; a < NA; a++) {
      pad_off[a] = off;
      int ntile = (total[a] + BM - 1) / BM;
      for (int tl = 0; tl < ntile; tl++) tileAdapter[off / BM + tl] = a;
      off += ntile * BM;
    }
    for (int tl = off / BM; tl < MTILES; tl++) tileAdapter[tl] = -1;
  }
  __syncthreads();
  for (int i = tid; i < MPAD; i += 256) tok[i] = -1;
  __syncthreads();
  int myoff[NA];
  for (int a = 0; a < NA; a++) myoff[a] = pad_off[a] + cnt[tid][a];
  for (int i = 0; i < CH; i++) {
    int a = widx[base + i];
    tok[myoff[a]++] = base + i;
  }
}

// ---------------------------------------------------------------------------
// Kernel 2: gather x rows into sorted order -> bf16 (cols 0..2047 of Xg).
// ---------------------------------------------------------------------------
__global__ void gather_kernel(const float* __restrict__ x,
                              const int* __restrict__ tok,
                              u16* __restrict__ Xg) {
  const int row = blockIdx.x;
  const int t = tok[row];
  const int tid = threadIdx.x;
  u16x8* dst = (u16x8*)(Xg + (size_t)row * KX);
  if (t < 0) {
    u16x8 z = {0, 0, 0, 0, 0, 0, 0, 0};
    dst[tid] = z;
    return;
  }
  const f32x4* src = (const f32x4*)(x + (size_t)t * DIN);
  f32x4 v0 = src[tid * 2];
  f32x4 v1 = src[tid * 2 + 1];
  u16x8 o;
  o[0] = f2bf(v0[0]); o[1] = f2bf(v0[1]); o[2] = f2bf(v0[2]); o[3] = f2bf(v0[3]);
  o[4] = f2bf(v1[0]); o[5] = f2bf(v1[1]); o[6] = f2bf(v1[2]); o[7] = f2bf(v1[3]);
  dst[tid] = o;
}

// ---------------------------------------------------------------------------
// Kernel 3: Xa partials.  Xa = Xg[:, :2048] @ A_qkv[a]  ([M x 48]).
// ---------------------------------------------------------------------------
__global__ __launch_bounds__(256) void xa_partial_kernel(
    const u16* __restrict__ Xg, const float* __restrict__ A_qkv,
    const int* __restrict__ tileAdapter, float* __restrict__ Ppart) {
  const int ks = blockIdx.y;
  const int ad = tileAdapter[blockIdx.x >> 1];
  const int a = ad < 0 ? 0 : ad;
  const int kb = ks * (DIN / KSPLIT);
  const int tid = threadIdx.x;
  const int rg = tid >> 2;
  const int jg = tid & 3;
  const int r0 = blockIdx.x * 128 + rg * 2;
  const int j0 = jg * 12;
  __shared__ float ldsA[64][56];
  float acc[2][12];
  #pragma unroll
  for (int r = 0; r < 2; r++)
    #pragma unroll
    for (int j = 0; j < 12; j++) acc[r][j] = 0.f;

  for (int kc = 0; kc < 2; kc++) {
    const int kbase = kb + kc * 64;
    for (int i = tid; i < 64 * 48; i += 256) {
      int kk = i / 48, j = i - kk * 48;
      ldsA[kk][j] = A_qkv[((size_t)a * DIN + kbase + kk) * (3 * RLORA) + j];
    }
    __syncthreads();
    u16x8 xr[2][8];
    #pragma unroll
    for (int r = 0; r < 2; r++)
      #pragma unroll
      for (int q = 0; q < 8; q++)
        xr[r][q] = *(const u16x8*)(Xg + (size_t)(r0 + r) * KX + kbase + q * 8);
    #pragma unroll
    for (int q = 0; q < 8; q++) {
      #pragma unroll
      for (int e = 0; e < 8; e++) {
        const int kk = q * 8 + e;
        f32x4 a0 = *(const f32x4*)&ldsA[kk][j0];
        f32x4 a1 = *(const f32x4*)&ldsA[kk][j0 + 4];
        f32x4 a2 = *(const f32x4*)&ldsA[kk][j0 + 8];
        float x0 = bf2f(xr[0][q][e]);
        float x1 = bf2f(xr[1][q][e]);
        #pragma unroll
        for (int c = 0; c < 4; c++) {
          acc[0][c]     += x0 * a0[c];  acc[1][c]     += x1 * a0[c];
          acc[0][4 + c] += x0 * a1[c];  acc[1][4 + c] += x1 * a1[c];
          acc[0][8 + c] += x0 * a2[c];  acc[1][8 + c] += x1 * a2[c];
        }
      }
    }
    __syncthreads();
  }
  #pragma unroll
  for (int r = 0; r < 2; r++)
    #pragma unroll
    for (int j = 0; j < 12; j++)
      Ppart[((size_t)ks * MPAD + r0 + r) * 48 + j0 + j] = acc[r][j];
}

// ---------------------------------------------------------------------------
// Kernel 4: reduce partials -> bf16 into Xg cols 2048..2111 (j>=48 zero).
// ---------------------------------------------------------------------------
__global__ void xa_reduce_kernel(const float* __restrict__ Ppart,
                                 u16* __restrict__ Xg) {
  const int gid = blockIdx.x * 256 + threadIdx.x;
  const int row = gid >> 6, j = gid & 63;
  float s = 0.f;
  if (j < 48) {
    #pragma unroll
    for (int sp = 0; sp < KSPLIT; sp++)
      s += Ppart[((size_t)sp * MPAD + row) * 48 + j];
  }
  Xg[(size_t)row * KX + DIN + j] = f2bf(s);
}

// ---------------------------------------------------------------------------
// Kernel 5: Weff[a][n][k] = W_base[n][k] + Delta[a][k][n], bf16, k<2048.
// ---------------------------------------------------------------------------
__global__ __launch_bounds__(256) void weff2_kernel(
    const float* __restrict__ W_base,
    const float* __restrict__ DW_q, const float* __restrict__ DW_kv,
    u16* __restrict__ Weff) {
  const int k0 = blockIdx.x * 64;
  const int n0 = blockIdx.y * 64;
  const int tid = threadIdx.x;
  const int k8 = (tid & 7) * 8;
  __shared__ float ldsD[64][65];

  f32x4 wb[2][2];
  #pragma unroll
  for (int h = 0; h < 2; h++) {
    const int nn = h * 32 + (tid >> 3);
    const float* p = W_base + (size_t)(n0 + nn) * DIN + k0 + k8;
    wb[h][0] = *(const f32x4*)p;
    wb[h][1] = *(const f32x4*)(p + 4);
  }

  const int ldD  = (n0 < DQ) ? DQ : 2 * DKV;
  const int ncol = (n0 < DQ) ? n0 : n0 - DQ;

  for (int a = 0; a < NA; a++) {
    const float* Dp = (n0 < DQ)
        ? DW_q  + (size_t)a * DIN * DQ + ncol
        : DW_kv + (size_t)a * DIN * (2 * DKV) + ncol;
    for (int i = tid; i < 64 * 64; i += 256) {
      int kk = i >> 6, nn2 = i & 63;
      ldsD[kk][nn2] = Dp[(size_t)(k0 + kk) * ldD + nn2];
    }
    __syncthreads();
    #pragma unroll
    for (int h = 0; h < 2; h++) {
      const int nn = h * 32 + (tid >> 3);
      u16x8 o;
      #pragma unroll
      for (int j = 0; j < 8; j++)
        o[j] = f2bf(wb[h][j >> 2][j & 3] + ldsD[k8 + j][nn]);
      *(u16x8*)(Weff + ((size_t)a * NOUT + n0 + nn) * KX + k0 + k8) = o;
    }
    __syncthreads();
  }
}

// ---------------------------------------------------------------------------
// Kernel 6: fill Weff[a][n][2048..2111] with scattered B (LoRA slots).
// ---------------------------------------------------------------------------
__global__ void wslots_kernel(const float* __restrict__ B_q,
                              const float* __restrict__ B_kv,
                              u16* __restrict__ Weff) {
  const int a = blockIdx.y;
  const int n = blockIdx.x * 256 + threadIdx.x;
  const int seg = n >> 11;   // 0=q, 1=k, 2=v
  u16 vals[64];
  #pragma unroll
  for (int j = 0; j < 64; j++) vals[j] = 0;
  if (seg == 0) {
    const float* Bp = B_q + ((size_t)a * RLORA) * DQ + n;
    #pragma unroll
    for (int r = 0; r < RLORA; r++) vals[r] = f2bf(Bp[(size_t)r * DQ]);
  } else if (seg == 1) {
    const float* Bp = B_kv + ((size_t)a * RLORA) * (2 * DKV) + (n - DQ);
    #pragma unroll
    for (int r = 0; r < RLORA; r++) vals[RLORA + r] = f2bf(Bp[(size_t)r * (2 * DKV)]);
  } else {
    const float* Bp = B_kv + ((size_t)a * RLORA) * (2 * DKV) + (n - DQ);
    #pragma unroll
    for (int r = 0; r < RLORA; r++) vals[2 * RLORA + r] = f2bf(Bp[(size_t)r * (2 * DKV)]);
  }
  u16* dst = Weff + ((size_t)a * NOUT + n) * KX + DIN;
  #pragma unroll
  for (int v = 0; v < 8; v++) *(u16x8*)(dst + v * 8) = *(u16x8*)(vals + v * 8);
}

// ---------------------------------------------------------------------------
// Kernel 7: grouped GEMM, 256x256 tile, BK=64, 8 waves (2Mx4N), m201-style
// 4-phase-per-K-tile schedule: per phase {ds_read quadrant frags || stage one
// 8KB unit x2} -> bar -> 16 MFMA (setprio) -> bar.  vmcnt(4) once per K-tile.
// B tile regrouped by n-half in LDS; XOR swizzle chunk^(row&7) on 128B rows.
// ---------------------------------------------------------------------------
#define BAR      asm volatile("s_barrier" ::: "memory")
#define WAITV(n) asm volatile("s_waitcnt vmcnt(" #n ")" ::: "memory")

#define RD_A(db, mh) { \
  _Pragma("unroll") for (int q = 0; q < 4; ++q) { \
    const char* rp = ldsc + (db)*32768 + (wm*128 + (mh)*64 + q*16 + fr)*128; \
    af[q][0] = *(const short8*)(rp + ck0); \
    af[q][1] = *(const short8*)(rp + ck1); } }

#define RD_B(db, nh, bfv) { \
  _Pragma("unroll") for (int q = 0; q < 2; ++q) { \
    const char* rp = ldsc + 65536 + (db)*32768 + ((nh)*128 + wn*32 + q*16 + fr)*128; \
    bfv[q][0] = *(const short8*)(rp + ck0); \
    bfv[q][1] = *(const short8*)(rp + ck1); } }

#define ST_A(db, mh, t) { \
  gl_lds16(gAsrc + (size_t)((mh)*64)*KX + (size_t)(t)*64, \
           ldsu + (db)*16384 + ((mh)*64*64) + stid); \
  gl_lds16(gAsrc + (size_t)(128 + (mh)*64)*KX + (size_t)(t)*64, \
           ldsu + (db)*16384 + ((128 + (mh)*64)*64) + stid); }

#define ST_B(db, nh, t) { \
  gl_lds16(gBsrc + (size_t)((nh)*32)*KX + (size_t)(t)*64, \
           ldsu + 32768 + (db)*16384 + ((nh)*128*64) + stid); \
  gl_lds16(gBsrc + (size_t)(128 + (nh)*32)*KX + (size_t)(t)*64, \
           ldsu + 32768 + (db)*16384 + (((nh)*128 + 64)*64) + stid); }

#define MM(mh, nh, bfv) { \
  __builtin_amdgcn_s_setprio(1); \
  _Pragma("unroll") for (int q = 0; q < 4; ++q) \
  _Pragma("unroll") for (int r = 0; r < 2; ++r) { \
    acc[(mh)*4+q][(nh)*2+r] = __builtin_amdgcn_mfma_f32_16x16x32_bf16( \
        af[q][0], bfv[r][0], acc[(mh)*4+q][(nh)*2+r], 0, 0, 0); \
    acc[(mh)*4+q][(nh)*2+r] = __builtin_amdgcn_mfma_f32_16x16x32_bf16( \
        af[q][1], bfv[r][1], acc[(mh)*4+q][(nh)*2+r], 0, 0, 0); } \
  __builtin_amdgcn_s_setprio(0); }

// standard K-tile: stages A-mh1/B-nh0 of t+1 (other db), A-mh0/B-nh1 of t+2
#define KT_STD(db, t) { \
  RD_A(db, 0); RD_B(db, 0, bf0); ST_A(1-(db), 1, (t)+1); BAR; MM(0, 0, bf0); BAR; \
  RD_B(db, 1, bf1);              ST_B(1-(db), 0, (t)+1); BAR; MM(0, 1, bf1); BAR; \
  RD_A(db, 1);                   ST_A(db, 0, (t)+2);     BAR; MM(1, 1, bf1); BAR; \
  ST_B(db, 1, (t)+2); WAITV(4);                          BAR; MM(1, 0, bf0); BAR; }

// t=31: only finish tile 32; drain fully so the last tile is ready
#define KT_T31(db, t) { \
  RD_A(db, 0); RD_B(db, 0, bf0); ST_A(1-(db), 1, (t)+1); BAR; MM(0, 0, bf0); BAR; \
  RD_B(db, 1, bf1);              ST_B(1-(db), 0, (t)+1); BAR; MM(0, 1, bf1); BAR; \
  RD_A(db, 1);                                           BAR; MM(1, 1, bf1); BAR; \
  WAITV(0);                                              BAR; MM(1, 0, bf0); BAR; }

#define KT_LAST(db) { \
  RD_A(db, 0); RD_B(db, 0, bf0); BAR; MM(0, 0, bf0); BAR; \
  RD_B(db, 1, bf1);              BAR; MM(0, 1, bf1); BAR; \
  RD_A(db, 1);                   BAR; MM(1, 1, bf1); BAR; \
                                 BAR; MM(1, 0, bf0); BAR; }

__global__ __launch_bounds__(512, 2) void gemm256_kernel(
    const u16* __restrict__ Xg, const u16* __restrict__ Weff,
    const int* __restrict__ tok, const int* __restrict__ tileAdapter,
    float* __restrict__ out) {
  __shared__ __align__(16) u16 Lds[65536];   // A[2][256*64] | B[2][256*64]

  const int bid = blockIdx.x;
  const int wg = (bid & 7) * (NWG / 8) + (bid >> 3);
  const int mt = wg % MTILES, nt = wg / MTILES;
  const int a = tileAdapter[mt];
  if (a < 0) return;
  const int m0 = mt * BM, n0 = nt * BN;

  const int tid = threadIdx.x;
  const int l = tid & 63, w = tid >> 6;
  const int wm = w >> 2, wn = w & 3;
  const int fr = l & 15;
  const int kq = l >> 4;
  const int s7 = l & 7;
  const int ck0 = ((kq ^ s7) << 4);
  const int ck1 = (((4 + kq) ^ s7) << 4);

  // staging lane constants (pre-swizzled source chunk = chunk ^ (row&7))
  const int l64 = tid >> 3;
  const int swc = (tid & 7) ^ (l64 & 7);
  const int stid = tid * 8;
  const u16* gAsrc = Xg + (size_t)(m0 + l64) * KX + swc * 8;
  const int nB = ((l64 >> 5) * 64) + (l64 & 31);
  const u16* gBsrc = Weff + ((size_t)a * NOUT + n0 + nB) * KX + swc * 8;

  u16* ldsu = &Lds[0];
  const char* ldsc = (const char*)ldsu;

  f32x4 acc[8][4];
  #pragma unroll
  for (int i = 0; i < 8; i++)
    #pragma unroll
    for (int j = 0; j < 4; j++) acc[i][j] = (f32x4){0.f, 0.f, 0.f, 0.f};

  short8 af[4][2], bf0[2][2], bf1[2][2];

  // prologue: tile0 (db0, all 4 units), then A-mh0(1), B-nh1(1) (db1)
  ST_A(0, 0, 0); ST_B(0, 0, 0); ST_A(0, 1, 0); ST_B(0, 1, 0);
  ST_A(1, 0, 1); ST_B(1, 1, 1);
  WAITV(4);   // retire tile0's 8 loads; keep the newest 4
  BAR;

  for (int p = 0; p < 15; ++p) {
    const int t0 = 2 * p;
    KT_STD(0, t0);
    KT_STD(1, t0 + 1);
  }
  KT_STD(0, 30);
  KT_T31(1, 31);
  KT_LAST(0);

  // C-write: scatter rows via tok
  #pragma unroll
  for (int mi = 0; mi < 8; ++mi) {
    const int rb = m0 + wm * 128 + mi * 16 + ((l >> 4) << 2);
    int tt[4];
    #pragma unroll
    for (int reg = 0; reg < 4; ++reg) tt[reg] = tok[rb + reg];
    #pragma unroll
    for (int ni = 0; ni < 4; ++ni) {
      const int col = n0 + wn * 64 + ni * 16 + fr;
      #pragma unroll
      for (int reg = 0; reg < 4; ++reg)
        if (tt[reg] >= 0) out[(size_t)tt[reg] * NOUT + col] = acc[mi][ni][reg];
    }
  }
}

// ---------------------------------------------------------------------------
// Fallback (ws too small): correct fp32 path.
// ---------------------------------------------------------------------------
__global__ void fallback_kernel(const float* __restrict__ x,
                                const float* __restrict__ W_base,
                                const float* __restrict__ A_qkv,
                                const float* __restrict__ B_q,
                                const float* __restrict__ B_kv,
                                const float* __restrict__ DW_q,
                                const float* __restrict__ DW_kv,
                                const int* __restrict__ widx,
                                float* __restrict__ out) {
  const int t = blockIdx.x;
  const int n = blockIdx.y * 256 + threadIdx.x;
  const int a = widx[t];
  __shared__ float xs[DIN];
  __shared__ float ys[3 * RLORA];
  for (int k = threadIdx.x; k < DIN; k += 256) xs[k] = x[(size_t)t * DIN + k];
  __syncthreads();
  if (threadIdx.x < 3 * RLORA) {
    float s = 0.f;
    const float* Ap = A_qkv + (size_t)a * DIN * (3 * RLORA) + threadIdx.x;
    for (int k = 0; k < DIN; k++) s += xs[k] * Ap[(size_t)k * (3 * RLORA)];
    ys[threadIdx.x] = s;
  }
  __syncthreads();
  const float* dcol; int ldD, roff; const float* bcol; int ldB;
  if (n < DQ) {
    dcol = DW_q + (size_t)a * DIN * DQ + n; ldD = DQ; roff = 0;
    bcol = B_q + (size_t)a * RLORA * DQ + n; ldB = DQ;
  } else {
    dcol = DW_kv + (size_t)a * DIN * (2 * DKV) + (n - DQ); ldD = 2 * DKV;
    roff = (n < 2 * DQ) ? RLORA : 2 * RLORA;
    bcol = B_kv + (size_t)a * RLORA * (2 * DKV) + (n - DQ); ldB = 2 * DKV;
  }
  const float* wrow = W_base + (size_t)n * DIN;
  float acc = 0.f;
  for (int k = 0; k < DIN; k++) acc += xs[k] * (wrow[k] + dcol[(size_t)k * ldD]);
  for (int r = 0; r < RLORA; r++) acc += ys[roff + r] * bcol[(size_t)r * ldB];
  out[(size_t)t * NOUT + n] = acc;
}

// ---------------------------------------------------------------------------
extern "C" void kernel_launch(void* const* d_in, const int* in_sizes, int n_in,
                              void* d_out, int out_size, void* d_ws, size_t ws_size,
                              hipStream_t stream) {
  const float* x      = (const float*)d_in[0];
  const float* W_base = (const float*)d_in[1];
  const float* A_qkv  = (const float*)d_in[2];
  const float* B_q    = (const float*)d_in[3];
  const float* B_kv   = (const float*)d_in[4];
  const float* DW_q   = (const float*)d_in[5];
  const float* DW_kv  = (const float*)d_in[6];
  const int*   widx   = (const int*)d_in[7];
  float* out = (float*)d_out;

  const size_t WEFF_BYTES = (size_t)NA * NOUT * KX * sizeof(u16);
  const size_t XG_BYTES   = (size_t)MPAD * KX * sizeof(u16);
  const size_t TOK_BYTES  = (size_t)MPAD * sizeof(int);
  const size_t TILE_BYTES = (size_t)MTILES * sizeof(int);
  const size_t need = WEFF_BYTES + XG_BYTES + TOK_BYTES + TILE_BYTES;

  if (ws_size < need) {
    fallback_kernel<<<dim3(T_TOK, NOUT / 256), 256, 0, stream>>>(
        x, W_base, A_qkv, B_q, B_kv, DW_q, DW_kv, widx, out);
    return;
  }

  char* ws = (char*)d_ws;
  u16* Weff = (u16*)ws;
  u16* Xg   = (u16*)(ws + WEFF_BYTES);
  int* tok  = (int*)(ws + WEFF_BYTES + XG_BYTES);
  int* tileAdapter = tok + MPAD;
  float* Ppart = (float*)ws;   // aliases Weff; consumed before weff2 writes

  prep_kernel<<<1, 256, 0, stream>>>(widx, tok, tileAdapter);
  gather_kernel<<<MPAD, 256, 0, stream>>>(x, tok, Xg);
  xa_partial_kernel<<<dim3(MPAD / 128, KSPLIT), 256, 0, stream>>>(
      Xg, A_qkv, tileAdapter, Ppart);
  xa_reduce_kernel<<<MPAD * 64 / 256, 256, 0, stream>>>(Ppart, Xg);
  weff2_kernel<<<dim3(DIN / 64, NOUT / 64), 256, 0, stream>>>(
      W_base, DW_q, DW_kv, Weff);
  wslots_kernel<<<dim3(NOUT / 256, NA), 256, 0, stream>>>(B_q, B_kv, Weff);
  gemm256_kernel<<<dim3(NWG), 512, 0, stream>>>(
      Xg, Weff, tok, tileAdapter, out);
}